// Round 6
// baseline (183.482 us; speedup 1.0000x reference)
//
#include <hip/hip_runtime.h>
#include <hip/hip_bf16.h>
#include <math.h>

#define N_TOK 4096
#define IN_CH 256
#define OUT_CH 64
#define HEADS 8
#define PROJ (OUT_CH * HEADS) /* 512 */
#define NLOG2E -1.44269504088896340736f

typedef float f32x4 __attribute__((ext_vector_type(4)));
typedef float f32x16 __attribute__((ext_vector_type(16)));
typedef __bf16 bf16x8 __attribute__((ext_vector_type(8)));
typedef unsigned short ushort_t;

__device__ inline ushort_t bf16rne(float x) {
    unsigned u = __float_as_uint(x);
    unsigned r = (u + 0x7FFFu + ((u >> 16) & 1u)) >> 16;
    return (ushort_t)r;
}

// packed f32->bf16x2 convert (RNE): D[15:0]=bf16(lo), D[31:16]=bf16(hi).
__device__ inline unsigned cvtpk_bf16(float lo, float hi) {
    unsigned d;
    asm("v_cvt_pk_bf16_f32 %0, %1, %2" : "=v"(d) : "v"(lo), "v"(hi));
    return d;
}
// v_permlane32_swap_b32 VDST, VSRC (R5-verified semantics):
// After PLSWAP(x, y):  x = {lo: own x,      hi: partner y}
//                      y = {lo: partner x,  hi: own y}
#define PLSWAP(x, y) asm("v_permlane32_swap_b32 %0, %1" : "+v"(x), "+v"(y))

// ---------------------------------------------------------------------------
// Kernel 0: cast X / Wq / Wk / Wv to bf16 AND pre-permute into MFMA fragment
// order:  flat index (((g*8 + k8)*4 + quad)*16 + t)*8  (g = 16-row group).
// Wq additionally scaled by -log2(e) so sigmoid = rcp(1 + exp2(t)).
// ---------------------------------------------------------------------------
__global__ __launch_bounds__(256) void cast_pack_kernel(
    const float* __restrict__ X,
    const float* __restrict__ Wq, const float* __restrict__ Wk,
    const float* __restrict__ Wv,
    ushort_t* __restrict__ Xa, ushort_t* __restrict__ Wp)
{
    const int i = blockIdx.x * 256 + threadIdx.x;
    const float* src;
    ushort_t* dst;
    float scale = 1.0f;
    if (i < 131072) {                       // X part: N*IN_CH/8 packs
        const int t = i & 15, quad = (i >> 4) & 3, k8 = (i >> 6) & 7, g = i >> 9;
        src = X + (size_t)(g * 16 + t) * IN_CH + k8 * 32 + quad * 8;
        dst = Xa + (size_t)i * 8;
    } else {                                // W part: 3*PROJ*IN_CH/8 packs
        const int j = i - 131072;
        const int z = j >> 14;
        const int r = j & 16383;
        const int cl = r & 15, quad = (r >> 4) & 3, k8 = (r >> 6) & 7, gc = r >> 9;
        const float* W = (z == 0) ? Wq : (z == 1) ? Wk : Wv;
        src = W + (size_t)(gc * 16 + cl) * IN_CH + k8 * 32 + quad * 8;
        dst = Wp + (size_t)z * 131072 * 8 + (size_t)r * 8;
        if (z == 0) scale = NLOG2E;
    }
    float4 a = *(const float4*)src;
    float4 b = *(const float4*)(src + 4);
    ushort_t pk[8];
    pk[0] = bf16rne(a.x * scale); pk[1] = bf16rne(a.y * scale);
    pk[2] = bf16rne(a.z * scale); pk[3] = bf16rne(a.w * scale);
    pk[4] = bf16rne(b.x * scale); pk[5] = bf16rne(b.y * scale);
    pk[6] = bf16rne(b.z * scale); pk[7] = bf16rne(b.w * scale);
    *(uint4*)dst = *(uint4*)pk;
}

// ---------------------------------------------------------------------------
// Kernel 1: Q/K/V projections via bf16 MFMA from frag-packed Xa/Wp.
// grid (PROJ/64, N/64, 3), block 256 (4 waves).  Wave w: 16 tokens x 64 cols.
// Epilogue routes through an LDS transpose so ALL global stores are coalesced
// uint4.  (Es tile is 64x64 ushorts; 256 threads store TWO uint4 each.)
//   z=0 -> Qb [N][PROJ] (pre-scaled by -log2e), z=1 -> Kb, z=2 -> Vt [H][64][N]
// ---------------------------------------------------------------------------
__global__ __launch_bounds__(256) void proj_mfma_kernel(
    const ushort_t* __restrict__ Xa, const ushort_t* __restrict__ Wp,
    const float* __restrict__ bq, const float* __restrict__ bk,
    const float* __restrict__ bv,
    ushort_t* __restrict__ Qb, ushort_t* __restrict__ Kb,
    ushort_t* __restrict__ Vt)
{
    const int z = blockIdx.z;
    const float* bias = (z == 0) ? bq : (z == 1) ? bk : bv;
    const float bscale = (z == 0) ? NLOG2E : 1.0f;
    const int c0 = blockIdx.x * 64;
    const int n0 = blockIdx.y * 64;

    const int tid = threadIdx.x;
    const int w = tid >> 6;
    const int lane = tid & 63;
    const int l15 = lane & 15;
    const int quad = lane >> 4;

    __shared__ ushort_t Es[64 * 68];   // epilogue transpose tile (8.7 KB)

    const ushort_t* xa = Xa + (size_t)(blockIdx.y * 4 + w) * 4096 + quad * 128 + l15 * 8;
    const ushort_t* wp0 = Wp + (size_t)z * 131072 * 8 +
                          (size_t)(blockIdx.x * 4) * 4096 + quad * 128 + l15 * 8;

    f32x4 acc[4] = {{0.f, 0.f, 0.f, 0.f}, {0.f, 0.f, 0.f, 0.f},
                    {0.f, 0.f, 0.f, 0.f}, {0.f, 0.f, 0.f, 0.f}};

#pragma unroll 2
    for (int k8 = 0; k8 < 8; ++k8) {
        bf16x8 a = *(const bf16x8*)(xa + k8 * 512);
#pragma unroll
        for (int f = 0; f < 4; ++f) {
            bf16x8 b = *(const bf16x8*)(wp0 + f * 4096 + k8 * 512);
            acc[f] = __builtin_amdgcn_mfma_f32_16x16x32_bf16(a, b, acc[f], 0, 0, 0);
        }
    }

    // bias + bf16 round into LDS (layout depends on z), then coalesced store
    if (z < 2) {
        // Es[tok][c]
#pragma unroll
        for (int f = 0; f < 4; ++f) {
            const float bb = bias[c0 + f * 16 + l15] * bscale;
#pragma unroll
            for (int r = 0; r < 4; ++r)
                Es[(w * 16 + quad * 4 + r) * 68 + f * 16 + l15] = bf16rne(acc[f][r] + bb);
        }
    } else {
        // Es[c][tok]
#pragma unroll
        for (int f = 0; f < 4; ++f) {
            const float bb = bias[c0 + f * 16 + l15];
#pragma unroll
            for (int r = 0; r < 4; ++r)
                Es[(f * 16 + l15) * 68 + w * 16 + quad * 4 + r] = bf16rne(acc[f][r] + bb);
        }
    }
    __syncthreads();

    const int erow = tid >> 2;            // 0..63
    const int ecol = (tid & 3) * 16;      // 0,16,32,48 (+8 second store)
    uint4 pk0 = *(uint4*)&Es[erow * 68 + ecol];
    uint4 pk1 = *(uint4*)&Es[erow * 68 + ecol + 8];
    if (z < 2) {
        ushort_t* out = z ? Kb : Qb;
        ushort_t* p = &out[(size_t)(n0 + erow) * PROJ + c0 + ecol];
        *(uint4*)p = pk0;
        *(uint4*)(p + 8) = pk1;
    } else {
        ushort_t* p = &Vt[(size_t)(c0 + erow) * N_TOK + n0 + ecol];
        *(uint4*)p = pk0;
        *(uint4*)(p + 8) = pk1;
    }
}

// ---------------------------------------------------------------------------
// Kernel 2 (R6): fused sigmoid attention, bf16 MFMA 32x32x16.
// R5 post-mortem: monolithic softmax (32 live p-floats + 16 dwords + s0/s1)
// pushed peak live regs > 128 -> scratch spill (FETCH +8MB, WRITE +16MB,
// 62us > R3's 59).  R6 keeps R5's wins (Ps LDS eliminated via T12
// cvt_pk+permlane32_swap; single barrier per tile via double-buffer) and
// splits each 64-key tile into TWO 32-key half-pipelines:
//     QK(0-31) -> sigmoid/pack -> PV(ks0,1)  then same for keys 32-63.
// Only 16 p-floats + 8 dwords live at once; s1 never coexists with p0;
// A-frags die into their MFMAs.  Peak ~100 regs < 128 budget.
// block 256 (4 waves x 32 q), grid (32, 8, ZS=4) = 1024 = 4/CU.
// DEN per-lane f32 + one __shfl_xor(32).
// PLSWAP pairing (R5-verified): A0.d0 = {lo: own d00, hi: partner d10}.
// ---------------------------------------------------------------------------
template<int ZS>
__global__ __launch_bounds__(256, 4) void attn_kernel(
    const ushort_t* __restrict__ Qb, const ushort_t* __restrict__ Kb,
    const ushort_t* __restrict__ Vt,
    float* __restrict__ NUM, float* __restrict__ DEN)
{
    constexpr int KEYS = N_TOK / ZS;      // keys per block
    constexpr int TILES = KEYS / 64;      // 64-key tiles per block

    const int h = blockIdx.y;
    const int z = blockIdx.z;
    const int n0 = blockIdx.x * 128;
    const int tid = threadIdx.x;
    const int w = tid >> 6;               // 0..3, wave owns queries w*32..+31
    const int lane = tid & 63;
    const int l31 = lane & 31;
    const int hf = lane >> 5;             // half-wave: k-chunk select

    __shared__ ushort_t Ks[2 * 64 * 64];  // [buf][key][d], xor-swizzled chunks
    __shared__ ushort_t Vs[2 * 64 * 64];  // [buf][d][key], xor-swizzled chunks

    // Q B-fragments, register-resident (pre-scaled by -log2e).
    bf16x8 qb[4];
    {
        const ushort_t* base = Qb + (size_t)(n0 + w * 32 + l31) * PROJ + h * 64 + hf * 8;
        qb[0] = *(const bf16x8*)(base);
        qb[1] = *(const bf16x8*)(base + 16);
        qb[2] = *(const bf16x8*)(base + 32);
        qb[3] = *(const bf16x8*)(base + 48);
    }

    f32x16 o0 = {};                       // O[q][d: 0..31]
    f32x16 o1 = {};                       // O[q][d: 32..63]
    float den = 0.0f;                     // per-lane partial DEN

    // staging geometry: thread -> (row, 2 consecutive chunks), xor-swizzled
    const int srow = tid >> 2;
    const int sc2 = (tid & 3) * 2;
    const int sp0 = (sc2 ^ (srow & 7)) * 8;
    const int sp1 = ((sc2 + 1) ^ (srow & 7)) * 8;
    const int xm = l31 & 7;               // fragment-read swizzle mask

    const ushort_t* kgp = Kb + (size_t)h * 64 + sc2 * 8 +
                          (size_t)(z * KEYS + srow) * PROJ;
    const ushort_t* vgp = Vt + (size_t)h * 64 * N_TOK + (size_t)srow * N_TOK +
                          sc2 * 8 + z * KEYS;

    // prologue: tile 0 -> buf0; prefetch tile 1 into regs
    uint4 kr0 = ((const uint4*)kgp)[0], kr1 = ((const uint4*)kgp)[1];
    uint4 vr0 = ((const uint4*)vgp)[0], vr1 = ((const uint4*)vgp)[1];
    *(uint4*)&Ks[srow * 64 + sp0] = kr0;
    *(uint4*)&Ks[srow * 64 + sp1] = kr1;
    *(uint4*)&Vs[srow * 64 + sp0] = vr0;
    *(uint4*)&Vs[srow * 64 + sp1] = vr1;
    if (TILES > 1) {
        kgp += 64 * PROJ; vgp += 64;
        kr0 = ((const uint4*)kgp)[0]; kr1 = ((const uint4*)kgp)[1];
        vr0 = ((const uint4*)vgp)[0]; vr1 = ((const uint4*)vgp)[1];
    }

    for (int lt = 0; lt < TILES; ++lt) {
        const int bo = (lt & 1) << 12;    // read-buffer offset (shorts)
        __syncthreads();                  // buf[lt&1] writes visible; all
                                          // waves done reading buf[lt^1]
        if (lt + 1 < TILES) {             // stage tile lt+1 into other buffer
            const int bw = ((lt + 1) & 1) << 12;
            *(uint4*)&Ks[bw + srow * 64 + sp0] = kr0;
            *(uint4*)&Ks[bw + srow * 64 + sp1] = kr1;
            *(uint4*)&Vs[bw + srow * 64 + sp0] = vr0;
            *(uint4*)&Vs[bw + srow * 64 + sp1] = vr1;
            if (lt + 2 < TILES) {         // prefetch tile lt+2
                kgp += 64 * PROJ; vgp += 64;
                kr0 = ((const uint4*)kgp)[0]; kr1 = ((const uint4*)kgp)[1];
                vr0 = ((const uint4*)vgp)[0]; vr1 = ((const uint4*)vgp)[1];
            }
        }

        float p[16];

        // ================= half A: keys 0-31 =================
        {
            f32x16 s0 = {};
            __builtin_amdgcn_s_setprio(1);
#pragma unroll
            for (int ks = 0; ks < 4; ++ks) {
                const int pos = ((ks * 2 + hf) ^ xm) * 8;
                bf16x8 ka = *(const bf16x8*)&Ks[bo + l31 * 64 + pos];
                s0 = __builtin_amdgcn_mfma_f32_32x32x16_bf16(ka, qb[ks], s0, 0, 0, 0);
            }
            __builtin_amdgcn_s_setprio(0);

#pragma unroll
            for (int r = 0; r < 16; ++r) {
                p[r] = __builtin_amdgcn_rcpf(1.0f + __builtin_amdgcn_exp2f(s0[r]));
                den += p[r];
            }
            unsigned d00 = cvtpk_bf16(p[0],  p[1]);
            unsigned d01 = cvtpk_bf16(p[2],  p[3]);
            unsigned d10 = cvtpk_bf16(p[4],  p[5]);
            unsigned d11 = cvtpk_bf16(p[6],  p[7]);
            unsigned d20 = cvtpk_bf16(p[8],  p[9]);
            unsigned d21 = cvtpk_bf16(p[10], p[11]);
            unsigned d30 = cvtpk_bf16(p[12], p[13]);
            unsigned d31 = cvtpk_bf16(p[14], p[15]);
            PLSWAP(d00, d10);
            PLSWAP(d01, d11);
            PLSWAP(d20, d30);
            PLSWAP(d21, d31);
            union { unsigned u[4]; bf16x8 v; } A0, A1;
            A0.u[0] = d00; A0.u[1] = d01; A0.u[2] = d10; A0.u[3] = d11;
            A1.u[0] = d20; A1.u[1] = d21; A1.u[2] = d30; A1.u[3] = d31;

            __builtin_amdgcn_s_setprio(1);
            {
                const int pos = ((0 + hf) ^ xm) * 8;          // ks=0
                bf16x8 vb0 = *(const bf16x8*)&Vs[bo + l31 * 64 + pos];
                o0 = __builtin_amdgcn_mfma_f32_32x32x16_bf16(A0.v, vb0, o0, 0, 0, 0);
                bf16x8 vb1 = *(const bf16x8*)&Vs[bo + (32 + l31) * 64 + pos];
                o1 = __builtin_amdgcn_mfma_f32_32x32x16_bf16(A0.v, vb1, o1, 0, 0, 0);
            }
            {
                const int pos = ((2 + hf) ^ xm) * 8;          // ks=1
                bf16x8 vb0 = *(const bf16x8*)&Vs[bo + l31 * 64 + pos];
                o0 = __builtin_amdgcn_mfma_f32_32x32x16_bf16(A1.v, vb0, o0, 0, 0, 0);
                bf16x8 vb1 = *(const bf16x8*)&Vs[bo + (32 + l31) * 64 + pos];
                o1 = __builtin_amdgcn_mfma_f32_32x32x16_bf16(A1.v, vb1, o1, 0, 0, 0);
            }
            __builtin_amdgcn_s_setprio(0);
        }

        // ================= half B: keys 32-63 =================
        {
            f32x16 s1 = {};
            __builtin_amdgcn_s_setprio(1);
#pragma unroll
            for (int ks = 0; ks < 4; ++ks) {
                const int pos = ((ks * 2 + hf) ^ xm) * 8;
                bf16x8 ka = *(const bf16x8*)&Ks[bo + (32 + l31) * 64 + pos];
                s1 = __builtin_amdgcn_mfma_f32_32x32x16_bf16(ka, qb[ks], s1, 0, 0, 0);
            }
            __builtin_amdgcn_s_setprio(0);

#pragma unroll
            for (int r = 0; r < 16; ++r) {
                p[r] = __builtin_amdgcn_rcpf(1.0f + __builtin_amdgcn_exp2f(s1[r]));
                den += p[r];
            }
            unsigned e00 = cvtpk_bf16(p[0],  p[1]);
            unsigned e01 = cvtpk_bf16(p[2],  p[3]);
            unsigned e10 = cvtpk_bf16(p[4],  p[5]);
            unsigned e11 = cvtpk_bf16(p[6],  p[7]);
            unsigned e20 = cvtpk_bf16(p[8],  p[9]);
            unsigned e21 = cvtpk_bf16(p[10], p[11]);
            unsigned e30 = cvtpk_bf16(p[12], p[13]);
            unsigned e31 = cvtpk_bf16(p[14], p[15]);
            PLSWAP(e00, e10);
            PLSWAP(e01, e11);
            PLSWAP(e20, e30);
            PLSWAP(e21, e31);
            union { unsigned u[4]; bf16x8 v; } A2, A3;
            A2.u[0] = e00; A2.u[1] = e01; A2.u[2] = e10; A2.u[3] = e11;
            A3.u[0] = e20; A3.u[1] = e21; A3.u[2] = e30; A3.u[3] = e31;

            __builtin_amdgcn_s_setprio(1);
            {
                const int pos = ((4 + hf) ^ xm) * 8;          // ks=2
                bf16x8 vb0 = *(const bf16x8*)&Vs[bo + l31 * 64 + pos];
                o0 = __builtin_amdgcn_mfma_f32_32x32x16_bf16(A2.v, vb0, o0, 0, 0, 0);
                bf16x8 vb1 = *(const bf16x8*)&Vs[bo + (32 + l31) * 64 + pos];
                o1 = __builtin_amdgcn_mfma_f32_32x32x16_bf16(A2.v, vb1, o1, 0, 0, 0);
            }
            {
                const int pos = ((6 + hf) ^ xm) * 8;          // ks=3
                bf16x8 vb0 = *(const bf16x8*)&Vs[bo + l31 * 64 + pos];
                o0 = __builtin_amdgcn_mfma_f32_32x32x16_bf16(A3.v, vb0, o0, 0, 0, 0);
                bf16x8 vb1 = *(const bf16x8*)&Vs[bo + (32 + l31) * 64 + pos];
                o1 = __builtin_amdgcn_mfma_f32_32x32x16_bf16(A3.v, vb1, o1, 0, 0, 0);
            }
            __builtin_amdgcn_s_setprio(0);
        }
    }

    // epilogue: unnormalized numerator.  q-row = (reg&3) + 8*(reg>>2) + 4*hf
#pragma unroll
    for (int rq = 0; rq < 4; ++rq) {
#pragma unroll
        for (int j = 0; j < 4; ++j) {
            const int q = n0 + w * 32 + rq * 8 + hf * 4 + j;
            float* p = &NUM[((size_t)z * N_TOK + q) * PROJ + h * 64 + l31];
            p[0]  = o0[rq * 4 + j];
            p[32] = o1[rq * 4 + j];
        }
    }
    // DEN: lane's den covers 32 keys of column q = l31; partner lane^32 has
    // the complementary 32.  Sum across halves, lanes 0..31 write.
    den += __shfl_xor(den, 32);
    if (lane < 32) {
        DEN[((size_t)z * N_TOK + n0 + w * 32 + lane) * HEADS + h] = den;
    }
}

// ---------------------------------------------------------------------------
// Kernel 3: out[n][d] = (1/8) * sum_h (sum_z NUM_z)/(sum_z DEN_z)
// ---------------------------------------------------------------------------
template<int ZS>
__global__ __launch_bounds__(256) void reduce_kernel(
    const float* __restrict__ NUM, const float* __restrict__ DEN,
    float* __restrict__ out)
{
    const int g = blockIdx.x * 256 + threadIdx.x;
    const int n = g >> 6;
    const int d = g & 63;
    float acc = 0.0f;
#pragma unroll
    for (int hh = 0; hh < HEADS; ++hh) {
        float num = 0.0f, dd = 0.0f;
#pragma unroll
        for (int zz = 0; zz < ZS; ++zz) {
            num += NUM[((size_t)zz * N_TOK + n) * PROJ + hh * 64 + d];
            dd  += DEN[((size_t)zz * N_TOK + n) * HEADS + hh];
        }
        acc += num / dd;
    }
    out[g] = acc * 0.125f;
}

extern "C" void kernel_launch(void* const* d_in, const int* in_sizes, int n_in,
                              void* d_out, int out_size, void* d_ws, size_t ws_size,
                              hipStream_t stream) {
    (void)in_sizes; (void)n_in; (void)out_size;
    const float* X  = (const float*)d_in[0];
    const float* Wq = (const float*)d_in[1];
    const float* bq = (const float*)d_in[2];
    const float* Wk = (const float*)d_in[3];
    const float* bk = (const float*)d_in[4];
    const float* Wv = (const float*)d_in[5];
    const float* bv = (const float*)d_in[6];
    float* out = (float*)d_out;

    // ws need at ZS=4: 33.55M (NUM) + 0.52M (DEN) + 12.58M (Qb/Kb/Vt)
    //                + 2.10M (Xa) + 0.79M (Wp) = 49.55 MB.  Fallback ZS=2.
    const size_t NEED4 =
        (size_t)4 * N_TOK * PROJ * 4 + (size_t)4 * N_TOK * HEADS * 4 +
        (size_t)3 * N_TOK * PROJ * 2 + (size_t)N_TOK * IN_CH * 2 +
        (size_t)3 * PROJ * IN_CH * 2;
    const int ZS = (ws_size >= NEED4) ? 4 : 2;

    float* NUM = (float*)d_ws;                              // [ZS][N][PROJ] f32
    float* DEN = NUM + (size_t)ZS * N_TOK * PROJ;           // [ZS][N][HEADS] f32
    ushort_t* Qb = (ushort_t*)(DEN + (size_t)ZS * N_TOK * HEADS);
    ushort_t* Kb = Qb + (size_t)N_TOK * PROJ;
    ushort_t* Vt = Kb + (size_t)N_TOK * PROJ;               // [H][64][N]
    ushort_t* Xa = Vt + (size_t)N_TOK * PROJ;               // frag-packed X
    ushort_t* Wp = Xa + (size_t)N_TOK * IN_CH;              // frag-packed W x3

    cast_pack_kernel<<<dim3(704), 256, 0, stream>>>(X, Wq, Wk, Wv, Xa, Wp);
    proj_mfma_kernel<<<dim3(PROJ / 64, N_TOK / 64, 3), 256, 0, stream>>>(
        Xa, Wp, bq, bk, bv, Qb, Kb, Vt);
    if (ZS == 4) {
        attn_kernel<4><<<dim3(N_TOK / 128, HEADS, 4), 256, 0, stream>>>(
            Qb, Kb, Vt, NUM, DEN);
        reduce_kernel<4><<<dim3(N_TOK * OUT_CH / 256), 256, 0, stream>>>(
            NUM, DEN, out);
    } else {
        attn_kernel<2><<<dim3(N_TOK / 128, HEADS, 2), 256, 0, stream>>>(
            Qb, Kb, Vt, NUM, DEN);
        reduce_kernel<2><<<dim3(N_TOK * OUT_CH / 256), 256, 0, stream>>>(
            NUM, DEN, out);
    }
}

// Round 7
// 140.958 us; speedup vs baseline: 1.3017x; 1.3017x over previous
//
#include <hip/hip_runtime.h>
#include <hip/hip_bf16.h>
#include <math.h>

#define N_TOK 4096
#define IN_CH 256
#define OUT_CH 64
#define HEADS 8
#define PROJ (OUT_CH * HEADS) /* 512 */
#define NLOG2E -1.44269504088896340736f

typedef float f32x4 __attribute__((ext_vector_type(4)));
typedef float f32x16 __attribute__((ext_vector_type(16)));
typedef __bf16 bf16x8 __attribute__((ext_vector_type(8)));
typedef unsigned short ushort_t;

__device__ inline ushort_t bf16rne(float x) {
    unsigned u = __float_as_uint(x);
    unsigned r = (u + 0x7FFFu + ((u >> 16) & 1u)) >> 16;
    return (ushort_t)r;
}

// packed f32->bf16x2 convert (RNE): D[15:0]=bf16(lo), D[31:16]=bf16(hi).
__device__ inline unsigned cvtpk_bf16(float lo, float hi) {
    unsigned d;
    asm("v_cvt_pk_bf16_f32 %0, %1, %2" : "=v"(d) : "v"(lo), "v"(hi));
    return d;
}
// v_permlane32_swap_b32 VDST, VSRC (R5-verified semantics):
// After PLSWAP(x, y):  x = {lo: own x,      hi: partner y}
//                      y = {lo: partner x,  hi: own y}
#define PLSWAP(x, y) asm("v_permlane32_swap_b32 %0, %1" : "+v"(x), "+v"(y))

// async global->LDS DMA, 16B per lane.  LDS dest = wave-uniform base +
// lane*16; swizzle achieved by pre-swizzling the per-lane GLOBAL address.
__device__ inline void gld_lds16(const ushort_t* g, ushort_t* l) {
    __builtin_amdgcn_global_load_lds(
        (const __attribute__((address_space(1))) unsigned int*)g,
        (__attribute__((address_space(3))) unsigned int*)l,
        16, 0, 0);
}

// ---------------------------------------------------------------------------
// Kernel 0: cast X / Wq / Wk / Wv to bf16 AND pre-permute into MFMA fragment
// order:  flat index (((g*8 + k8)*4 + quad)*16 + t)*8  (g = 16-row group).
// Wq additionally scaled by -log2(e) so sigmoid = rcp(1 + exp2(t)).
// ---------------------------------------------------------------------------
__global__ __launch_bounds__(256) void cast_pack_kernel(
    const float* __restrict__ X,
    const float* __restrict__ Wq, const float* __restrict__ Wk,
    const float* __restrict__ Wv,
    ushort_t* __restrict__ Xa, ushort_t* __restrict__ Wp)
{
    const int i = blockIdx.x * 256 + threadIdx.x;
    const float* src;
    ushort_t* dst;
    float scale = 1.0f;
    if (i < 131072) {                       // X part: N*IN_CH/8 packs
        const int t = i & 15, quad = (i >> 4) & 3, k8 = (i >> 6) & 7, g = i >> 9;
        src = X + (size_t)(g * 16 + t) * IN_CH + k8 * 32 + quad * 8;
        dst = Xa + (size_t)i * 8;
    } else {                                // W part: 3*PROJ*IN_CH/8 packs
        const int j = i - 131072;
        const int z = j >> 14;
        const int r = j & 16383;
        const int cl = r & 15, quad = (r >> 4) & 3, k8 = (r >> 6) & 7, gc = r >> 9;
        const float* W = (z == 0) ? Wq : (z == 1) ? Wk : Wv;
        src = W + (size_t)(gc * 16 + cl) * IN_CH + k8 * 32 + quad * 8;
        dst = Wp + (size_t)z * 131072 * 8 + (size_t)r * 8;
        if (z == 0) scale = NLOG2E;
    }
    float4 a = *(const float4*)src;
    float4 b = *(const float4*)(src + 4);
    ushort_t pk[8];
    pk[0] = bf16rne(a.x * scale); pk[1] = bf16rne(a.y * scale);
    pk[2] = bf16rne(a.z * scale); pk[3] = bf16rne(a.w * scale);
    pk[4] = bf16rne(b.x * scale); pk[5] = bf16rne(b.y * scale);
    pk[6] = bf16rne(b.z * scale); pk[7] = bf16rne(b.w * scale);
    *(uint4*)dst = *(uint4*)pk;
}

// ---------------------------------------------------------------------------
// Kernel 1: Q/K/V projections via bf16 MFMA from frag-packed Xa/Wp.
// grid (PROJ/64, N/64, 3), block 256 (4 waves).  Wave w: 16 tokens x 64 cols.
// Epilogue routes through an LDS transpose so ALL global stores are coalesced
// uint4.  (Es tile is 64x64 ushorts; 256 threads store TWO uint4 each.)
//   z=0 -> Qb [N][PROJ] (pre-scaled by -log2e), z=1 -> Kb, z=2 -> Vt [H][64][N]
// ---------------------------------------------------------------------------
__global__ __launch_bounds__(256) void proj_mfma_kernel(
    const ushort_t* __restrict__ Xa, const ushort_t* __restrict__ Wp,
    const float* __restrict__ bq, const float* __restrict__ bk,
    const float* __restrict__ bv,
    ushort_t* __restrict__ Qb, ushort_t* __restrict__ Kb,
    ushort_t* __restrict__ Vt)
{
    const int z = blockIdx.z;
    const float* bias = (z == 0) ? bq : (z == 1) ? bk : bv;
    const float bscale = (z == 0) ? NLOG2E : 1.0f;
    const int c0 = blockIdx.x * 64;
    const int n0 = blockIdx.y * 64;

    const int tid = threadIdx.x;
    const int w = tid >> 6;
    const int lane = tid & 63;
    const int l15 = lane & 15;
    const int quad = lane >> 4;

    __shared__ ushort_t Es[64 * 68];   // epilogue transpose tile (8.7 KB)

    const ushort_t* xa = Xa + (size_t)(blockIdx.y * 4 + w) * 4096 + quad * 128 + l15 * 8;
    const ushort_t* wp0 = Wp + (size_t)z * 131072 * 8 +
                          (size_t)(blockIdx.x * 4) * 4096 + quad * 128 + l15 * 8;

    f32x4 acc[4] = {{0.f, 0.f, 0.f, 0.f}, {0.f, 0.f, 0.f, 0.f},
                    {0.f, 0.f, 0.f, 0.f}, {0.f, 0.f, 0.f, 0.f}};

#pragma unroll 2
    for (int k8 = 0; k8 < 8; ++k8) {
        bf16x8 a = *(const bf16x8*)(xa + k8 * 512);
#pragma unroll
        for (int f = 0; f < 4; ++f) {
            bf16x8 b = *(const bf16x8*)(wp0 + f * 4096 + k8 * 512);
            acc[f] = __builtin_amdgcn_mfma_f32_16x16x32_bf16(a, b, acc[f], 0, 0, 0);
        }
    }

    // bias + bf16 round into LDS (layout depends on z), then coalesced store
    if (z < 2) {
        // Es[tok][c]
#pragma unroll
        for (int f = 0; f < 4; ++f) {
            const float bb = bias[c0 + f * 16 + l15] * bscale;
#pragma unroll
            for (int r = 0; r < 4; ++r)
                Es[(w * 16 + quad * 4 + r) * 68 + f * 16 + l15] = bf16rne(acc[f][r] + bb);
        }
    } else {
        // Es[c][tok]
#pragma unroll
        for (int f = 0; f < 4; ++f) {
            const float bb = bias[c0 + f * 16 + l15];
#pragma unroll
            for (int r = 0; r < 4; ++r)
                Es[(f * 16 + l15) * 68 + w * 16 + quad * 4 + r] = bf16rne(acc[f][r] + bb);
        }
    }
    __syncthreads();

    const int erow = tid >> 2;            // 0..63
    const int ecol = (tid & 3) * 16;      // 0,16,32,48 (+8 second store)
    uint4 pk0 = *(uint4*)&Es[erow * 68 + ecol];
    uint4 pk1 = *(uint4*)&Es[erow * 68 + ecol + 8];
    if (z < 2) {
        ushort_t* out = z ? Kb : Qb;
        ushort_t* p = &out[(size_t)(n0 + erow) * PROJ + c0 + ecol];
        *(uint4*)p = pk0;
        *(uint4*)(p + 8) = pk1;
    } else {
        ushort_t* p = &Vt[(size_t)(c0 + erow) * N_TOK + n0 + ecol];
        *(uint4*)p = pk0;
        *(uint4*)(p + 8) = pk1;
    }
}

// ---------------------------------------------------------------------------
// Kernel 2 (R7): fused sigmoid attention, bf16 MFMA 32x32x16.
// R6 post-mortem: VGPR_Count pinned at 64 across R3/R5/R6 -> unified-RF
// split gives VALU only ~64 arch VGPRs (o/s accumulators own an AGPR bank);
// R5/R6's softmax+prefetch state spilled to scratch (FETCH 137 MB).
// R7: staging via global_load_lds DMA (T-cat #1):
//   - zero prefetch registers, zero ds_write instructions;
//   - swizzle moved to the per-lane GLOBAL source address (m173 pattern):
//     lane (row=lane>>3, pc=lane&7) fetches logical chunk pc^row so the
//     linear DMA write (base + lane*16B) lands the swizzled layout;
//   - __syncthreads' vmcnt(0) drain before s_barrier synchronizes the DMA;
//     loads for tile t+1 fly under tile t's whole compute.
// Arch-VGPR demand ~48 < 64 even if the scheduler merges both halves.
// Keeps: Ps-LDS-free softmax (T12 cvt_pk + permlane32_swap, R5-verified
// pairing), double-buffered K/V, one barrier/tile, 32-key half-pipelines.
// block 256 (4 waves x 32 q), grid (32, 8, ZS=4) = 1024 = 4/CU.
// ---------------------------------------------------------------------------
template<int ZS>
__global__ __launch_bounds__(256, 4) void attn_kernel(
    const ushort_t* __restrict__ Qb, const ushort_t* __restrict__ Kb,
    const ushort_t* __restrict__ Vt,
    float* __restrict__ NUM, float* __restrict__ DEN)
{
    constexpr int KEYS = N_TOK / ZS;      // keys per block
    constexpr int TILES = KEYS / 64;      // 64-key tiles per block

    const int h = blockIdx.y;
    const int z = blockIdx.z;
    const int n0 = blockIdx.x * 128;
    const int tid = threadIdx.x;
    const int w = tid >> 6;               // 0..3, wave owns queries w*32..+31
    const int lane = tid & 63;
    const int l31 = lane & 31;
    const int hf = lane >> 5;             // half-wave: k-chunk select

    __shared__ ushort_t Ks[2 * 64 * 64];  // [buf][key][d], xor-swizzled chunks
    __shared__ ushort_t Vs[2 * 64 * 64];  // [buf][d][key], xor-swizzled chunks

    // Q B-fragments, register-resident (pre-scaled by -log2e).
    bf16x8 qb[4];
    {
        const ushort_t* base = Qb + (size_t)(n0 + w * 32 + l31) * PROJ + h * 64 + hf * 8;
        qb[0] = *(const bf16x8*)(base);
        qb[1] = *(const bf16x8*)(base + 16);
        qb[2] = *(const bf16x8*)(base + 32);
        qb[3] = *(const bf16x8*)(base + 48);
    }

    f32x16 o0 = {};                       // O[q][d: 0..31]
    f32x16 o1 = {};                       // O[q][d: 32..63]
    float den = 0.0f;                     // per-lane partial DEN

    // DMA staging geometry: wave w covers rows w*16..w*16+15 in two issues
    // of 8 rows; lane -> (row = r0 + (lane>>3), physical chunk = lane&7).
    // Global source fetches logical chunk pc ^ (row&7) = pc ^ lrow.
    const int lrow = lane >> 3;
    const int pc = lane & 7;
    const int swz = (pc ^ lrow) * 8;      // shorts
    const int lb = w * 1024;              // wave's LDS base (shorts)
    const ushort_t* kg = Kb + (size_t)h * 64 +
                         ((size_t)z * KEYS + w * 16 + lrow) * PROJ + swz;
    const ushort_t* vg = Vt + ((size_t)h * 64 + w * 16 + lrow) * N_TOK +
                         (size_t)z * KEYS + swz;

    const int xm = l31 & 7;               // fragment-read swizzle mask

    // prologue: stage tile 0 -> buf 0 (drained by first loop barrier)
    gld_lds16(kg,             &Ks[lb]);
    gld_lds16(kg + 8 * PROJ,  &Ks[lb + 512]);
    gld_lds16(vg,             &Vs[lb]);
    gld_lds16(vg + 8 * N_TOK, &Vs[lb + 512]);
    kg += 64 * PROJ;
    vg += 64;

    for (int lt = 0; lt < TILES; ++lt) {
        const int bo = (lt & 1) << 12;    // read-buffer offset (shorts)
        __syncthreads();                  // vmcnt(0)+barrier: buf[lt&1] ready,
                                          // all waves done with buf[lt^1]
        if (lt + 1 < TILES) {             // DMA tile lt+1 into other buffer
            const int bw = ((lt + 1) & 1) << 12;
            gld_lds16(kg,             &Ks[bw + lb]);
            gld_lds16(kg + 8 * PROJ,  &Ks[bw + lb + 512]);
            gld_lds16(vg,             &Vs[bw + lb]);
            gld_lds16(vg + 8 * N_TOK, &Vs[bw + lb + 512]);
            kg += 64 * PROJ;
            vg += 64;
        }

        // ================= half A: keys 0-31 =================
        {
            f32x16 s0 = {};
            __builtin_amdgcn_s_setprio(1);
#pragma unroll
            for (int ks = 0; ks < 4; ++ks) {
                const int pos = ((ks * 2 + hf) ^ xm) * 8;
                bf16x8 ka = *(const bf16x8*)&Ks[bo + l31 * 64 + pos];
                s0 = __builtin_amdgcn_mfma_f32_32x32x16_bf16(ka, qb[ks], s0, 0, 0, 0);
            }
            __builtin_amdgcn_s_setprio(0);

            float p[16];
#pragma unroll
            for (int r = 0; r < 16; ++r) {
                p[r] = __builtin_amdgcn_rcpf(1.0f + __builtin_amdgcn_exp2f(s0[r]));
                den += p[r];
            }
            unsigned d00 = cvtpk_bf16(p[0],  p[1]);
            unsigned d01 = cvtpk_bf16(p[2],  p[3]);
            unsigned d10 = cvtpk_bf16(p[4],  p[5]);
            unsigned d11 = cvtpk_bf16(p[6],  p[7]);
            unsigned d20 = cvtpk_bf16(p[8],  p[9]);
            unsigned d21 = cvtpk_bf16(p[10], p[11]);
            unsigned d30 = cvtpk_bf16(p[12], p[13]);
            unsigned d31 = cvtpk_bf16(p[14], p[15]);
            PLSWAP(d00, d10);
            PLSWAP(d01, d11);
            PLSWAP(d20, d30);
            PLSWAP(d21, d31);
            union { unsigned u[4]; bf16x8 v; } A0, A1;
            A0.u[0] = d00; A0.u[1] = d01; A0.u[2] = d10; A0.u[3] = d11;
            A1.u[0] = d20; A1.u[1] = d21; A1.u[2] = d30; A1.u[3] = d31;

            __builtin_amdgcn_s_setprio(1);
            {
                const int pos = ((0 + hf) ^ xm) * 8;          // ks=0
                bf16x8 vb0 = *(const bf16x8*)&Vs[bo + l31 * 64 + pos];
                o0 = __builtin_amdgcn_mfma_f32_32x32x16_bf16(A0.v, vb0, o0, 0, 0, 0);
                bf16x8 vb1 = *(const bf16x8*)&Vs[bo + (32 + l31) * 64 + pos];
                o1 = __builtin_amdgcn_mfma_f32_32x32x16_bf16(A0.v, vb1, o1, 0, 0, 0);
            }
            {
                const int pos = ((2 + hf) ^ xm) * 8;          // ks=1
                bf16x8 vb0 = *(const bf16x8*)&Vs[bo + l31 * 64 + pos];
                o0 = __builtin_amdgcn_mfma_f32_32x32x16_bf16(A1.v, vb0, o0, 0, 0, 0);
                bf16x8 vb1 = *(const bf16x8*)&Vs[bo + (32 + l31) * 64 + pos];
                o1 = __builtin_amdgcn_mfma_f32_32x32x16_bf16(A1.v, vb1, o1, 0, 0, 0);
            }
            __builtin_amdgcn_s_setprio(0);
        }

        // ================= half B: keys 32-63 =================
        {
            f32x16 s1 = {};
            __builtin_amdgcn_s_setprio(1);
#pragma unroll
            for (int ks = 0; ks < 4; ++ks) {
                const int pos = ((ks * 2 + hf) ^ xm) * 8;
                bf16x8 ka = *(const bf16x8*)&Ks[bo + (32 + l31) * 64 + pos];
                s1 = __builtin_amdgcn_mfma_f32_32x32x16_bf16(ka, qb[ks], s1, 0, 0, 0);
            }
            __builtin_amdgcn_s_setprio(0);

            float p[16];
#pragma unroll
            for (int r = 0; r < 16; ++r) {
                p[r] = __builtin_amdgcn_rcpf(1.0f + __builtin_amdgcn_exp2f(s1[r]));
                den += p[r];
            }
            unsigned e00 = cvtpk_bf16(p[0],  p[1]);
            unsigned e01 = cvtpk_bf16(p[2],  p[3]);
            unsigned e10 = cvtpk_bf16(p[4],  p[5]);
            unsigned e11 = cvtpk_bf16(p[6],  p[7]);
            unsigned e20 = cvtpk_bf16(p[8],  p[9]);
            unsigned e21 = cvtpk_bf16(p[10], p[11]);
            unsigned e30 = cvtpk_bf16(p[12], p[13]);
            unsigned e31 = cvtpk_bf16(p[14], p[15]);
            PLSWAP(e00, e10);
            PLSWAP(e01, e11);
            PLSWAP(e20, e30);
            PLSWAP(e21, e31);
            union { unsigned u[4]; bf16x8 v; } A2, A3;
            A2.u[0] = e00; A2.u[1] = e01; A2.u[2] = e10; A2.u[3] = e11;
            A3.u[0] = e20; A3.u[1] = e21; A3.u[2] = e30; A3.u[3] = e31;

            __builtin_amdgcn_s_setprio(1);
            {
                const int pos = ((4 + hf) ^ xm) * 8;          // ks=2
                bf16x8 vb0 = *(const bf16x8*)&Vs[bo + l31 * 64 + pos];
                o0 = __builtin_amdgcn_mfma_f32_32x32x16_bf16(A2.v, vb0, o0, 0, 0, 0);
                bf16x8 vb1 = *(const bf16x8*)&Vs[bo + (32 + l31) * 64 + pos];
                o1 = __builtin_amdgcn_mfma_f32_32x32x16_bf16(A2.v, vb1, o1, 0, 0, 0);
            }
            {
                const int pos = ((6 + hf) ^ xm) * 8;          // ks=3
                bf16x8 vb0 = *(const bf16x8*)&Vs[bo + l31 * 64 + pos];
                o0 = __builtin_amdgcn_mfma_f32_32x32x16_bf16(A3.v, vb0, o0, 0, 0, 0);
                bf16x8 vb1 = *(const bf16x8*)&Vs[bo + (32 + l31) * 64 + pos];
                o1 = __builtin_amdgcn_mfma_f32_32x32x16_bf16(A3.v, vb1, o1, 0, 0, 0);
            }
            __builtin_amdgcn_s_setprio(0);
        }
    }

    // epilogue: unnormalized numerator.  q-row = (reg&3) + 8*(reg>>2) + 4*hf
#pragma unroll
    for (int rq = 0; rq < 4; ++rq) {
#pragma unroll
        for (int j = 0; j < 4; ++j) {
            const int q = n0 + w * 32 + rq * 8 + hf * 4 + j;
            float* np_ = &NUM[((size_t)z * N_TOK + q) * PROJ + h * 64 + l31];
            np_[0]  = o0[rq * 4 + j];
            np_[32] = o1[rq * 4 + j];
        }
    }
    // DEN: lane's den covers 32 keys of column q = l31; partner lane^32 has
    // the complementary 32.  Sum across halves, lanes 0..31 write.
    den += __shfl_xor(den, 32);
    if (lane < 32) {
        DEN[((size_t)z * N_TOK + n0 + w * 32 + lane) * HEADS + h] = den;
    }
}

// ---------------------------------------------------------------------------
// Kernel 3: out[n][d] = (1/8) * sum_h (sum_z NUM_z)/(sum_z DEN_z)
// ---------------------------------------------------------------------------
template<int ZS>
__global__ __launch_bounds__(256) void reduce_kernel(
    const float* __restrict__ NUM, const float* __restrict__ DEN,
    float* __restrict__ out)
{
    const int g = blockIdx.x * 256 + threadIdx.x;
    const int n = g >> 6;
    const int d = g & 63;
    float acc = 0.0f;
#pragma unroll
    for (int hh = 0; hh < HEADS; ++hh) {
        float num = 0.0f, dd = 0.0f;
#pragma unroll
        for (int zz = 0; zz < ZS; ++zz) {
            num += NUM[((size_t)zz * N_TOK + n) * PROJ + hh * 64 + d];
            dd  += DEN[((size_t)zz * N_TOK + n) * HEADS + hh];
        }
        acc += num / dd;
    }
    out[g] = acc * 0.125f;
}

extern "C" void kernel_launch(void* const* d_in, const int* in_sizes, int n_in,
                              void* d_out, int out_size, void* d_ws, size_t ws_size,
                              hipStream_t stream) {
    (void)in_sizes; (void)n_in; (void)out_size;
    const float* X  = (const float*)d_in[0];
    const float* Wq = (const float*)d_in[1];
    const float* bq = (const float*)d_in[2];
    const float* Wk = (const float*)d_in[3];
    const float* bk = (const float*)d_in[4];
    const float* Wv = (const float*)d_in[5];
    const float* bv = (const float*)d_in[6];
    float* out = (float*)d_out;

    // ws need at ZS=4: 33.55M (NUM) + 0.52M (DEN) + 12.58M (Qb/Kb/Vt)
    //                + 2.10M (Xa) + 0.79M (Wp) = 49.55 MB.  Fallback ZS=2.
    const size_t NEED4 =
        (size_t)4 * N_TOK * PROJ * 4 + (size_t)4 * N_TOK * HEADS * 4 +
        (size_t)3 * N_TOK * PROJ * 2 + (size_t)N_TOK * IN_CH * 2 +
        (size_t)3 * PROJ * IN_CH * 2;
    const int ZS = (ws_size >= NEED4) ? 4 : 2;

    float* NUM = (float*)d_ws;                              // [ZS][N][PROJ] f32
    float* DEN = NUM + (size_t)ZS * N_TOK * PROJ;           // [ZS][N][HEADS] f32
    ushort_t* Qb = (ushort_t*)(DEN + (size_t)ZS * N_TOK * HEADS);
    ushort_t* Kb = Qb + (size_t)N_TOK * PROJ;
    ushort_t* Vt = Kb + (size_t)N_TOK * PROJ;               // [H][64][N]
    ushort_t* Xa = Vt + (size_t)N_TOK * PROJ;               // frag-packed X
    ushort_t* Wp = Xa + (size_t)N_TOK * IN_CH;              // frag-packed W x3

    cast_pack_kernel<<<dim3(704), 256, 0, stream>>>(X, Wq, Wk, Wv, Xa, Wp);
    proj_mfma_kernel<<<dim3(PROJ / 64, N_TOK / 64, 3), 256, 0, stream>>>(
        Xa, Wp, bq, bk, bv, Qb, Kb, Vt);
    if (ZS == 4) {
        attn_kernel<4><<<dim3(N_TOK / 128, HEADS, 4), 256, 0, stream>>>(
            Qb, Kb, Vt, NUM, DEN);
        reduce_kernel<4><<<dim3(N_TOK * OUT_CH / 256), 256, 0, stream>>>(
            NUM, DEN, out);
    } else {
        attn_kernel<2><<<dim3(N_TOK / 128, HEADS, 2), 256, 0, stream>>>(
            Qb, Kb, Vt, NUM, DEN);
        reduce_kernel<2><<<dim3(N_TOK * OUT_CH / 256), 256, 0, stream>>>(
            NUM, DEN, out);
    }
}

// Round 10
// 138.964 us; speedup vs baseline: 1.3204x; 1.0143x over previous
//
#include <hip/hip_runtime.h>
#include <hip/hip_bf16.h>
#include <math.h>

#define N_TOK 4096
#define IN_CH 256
#define OUT_CH 64
#define HEADS 8
#define PROJ (OUT_CH * HEADS) /* 512 */
#define NLOG2E -1.44269504088896340736f

typedef float f32x4 __attribute__((ext_vector_type(4)));
typedef float f32x16 __attribute__((ext_vector_type(16)));
typedef __bf16 bf16x8 __attribute__((ext_vector_type(8)));
typedef unsigned short ushort_t;

__device__ inline ushort_t bf16rne(float x) {
    unsigned u = __float_as_uint(x);
    unsigned r = (u + 0x7FFFu + ((u >> 16) & 1u)) >> 16;
    return (ushort_t)r;
}

// packed f32->bf16x2 convert (RNE): D[15:0]=bf16(lo), D[31:16]=bf16(hi).
__device__ inline unsigned cvtpk_bf16(float lo, float hi) {
    unsigned d;
    asm("v_cvt_pk_bf16_f32 %0, %1, %2" : "=v"(d) : "v"(lo), "v"(hi));
    return d;
}
// v_permlane32_swap_b32 VDST, VSRC (R5-verified semantics):
// After PLSWAP(x, y):  x = {lo: own x,      hi: partner y}
//                      y = {lo: partner x,  hi: own y}
#define PLSWAP(x, y) asm("v_permlane32_swap_b32 %0, %1" : "+v"(x), "+v"(y))

// NOTE (R10): the SIGPK fused-softmax macro is DELETED.  R8 and R9 failed
// with bit-identical absmax 860.033; SIGPK was the only delta common to
// both vs proven-R7, despite being arithmetically identical in source.
// Suspected codegen-level issue; softmax reverted to R7's p[16] form.

// async global->LDS DMA, 16B per lane.  LDS dest = wave-uniform base +
// lane*16; swizzle achieved by pre-swizzling the per-lane GLOBAL address.
__device__ inline void gld_lds16(const ushort_t* g, ushort_t* l) {
    __builtin_amdgcn_global_load_lds(
        (const __attribute__((address_space(1))) unsigned int*)g,
        (__attribute__((address_space(3))) unsigned int*)l,
        16, 0, 0);
}

// ---------------------------------------------------------------------------
// Kernel 0: cast X / Wq / Wk / Wv to bf16 AND pre-permute into MFMA fragment
// order:  flat index (((g*8 + k8)*4 + quad)*16 + t)*8  (g = 16-row group).
// Wq additionally scaled by -log2(e) so sigmoid = rcp(1 + exp2(t)).
// ---------------------------------------------------------------------------
__global__ __launch_bounds__(256) void cast_pack_kernel(
    const float* __restrict__ X,
    const float* __restrict__ Wq, const float* __restrict__ Wk,
    const float* __restrict__ Wv,
    ushort_t* __restrict__ Xa, ushort_t* __restrict__ Wp)
{
    const int i = blockIdx.x * 256 + threadIdx.x;
    const float* src;
    ushort_t* dst;
    float scale = 1.0f;
    if (i < 131072) {                       // X part: N*IN_CH/8 packs
        const int t = i & 15, quad = (i >> 4) & 3, k8 = (i >> 6) & 7, g = i >> 9;
        src = X + (size_t)(g * 16 + t) * IN_CH + k8 * 32 + quad * 8;
        dst = Xa + (size_t)i * 8;
    } else {                                // W part: 3*PROJ*IN_CH/8 packs
        const int j = i - 131072;
        const int z = j >> 14;
        const int r = j & 16383;
        const int cl = r & 15, quad = (r >> 4) & 3, k8 = (r >> 6) & 7, gc = r >> 9;
        const float* W = (z == 0) ? Wq : (z == 1) ? Wk : Wv;
        src = W + (size_t)(gc * 16 + cl) * IN_CH + k8 * 32 + quad * 8;
        dst = Wp + (size_t)z * 131072 * 8 + (size_t)r * 8;
        if (z == 0) scale = NLOG2E;
    }
    float4 a = *(const float4*)src;
    float4 b = *(const float4*)(src + 4);
    ushort_t pk[8];
    pk[0] = bf16rne(a.x * scale); pk[1] = bf16rne(a.y * scale);
    pk[2] = bf16rne(a.z * scale); pk[3] = bf16rne(a.w * scale);
    pk[4] = bf16rne(b.x * scale); pk[5] = bf16rne(b.y * scale);
    pk[6] = bf16rne(b.z * scale); pk[7] = bf16rne(b.w * scale);
    *(uint4*)dst = *(uint4*)pk;
}

// ---------------------------------------------------------------------------
// Kernel 1 (R10 = R8's DMA version): Q/K/V projections via bf16 MFMA.
// grid (PROJ/64, N/64, 3), block 256 (4 waves).  Wave w: 16 tokens x 64 cols.
// W staged through LDS via global_load_lds DMA, double-buffered per
// k8-slice.  Wave w stages col-group w's 1 KB slice (one DMA per thread
// per k8); all waves read all col-groups from LDS (linear, conflict-free).
// Global traffic/block: 160 -> 64 KB; b-operand latency L2 -> LDS.
// (Indexing identity: quad*128 + l15*8 == lane*8, so the DMA source/LDS
// read reproduce the original per-lane fragment addresses exactly.)
// Epilogue (unchanged): LDS transpose so all global stores are uint4.
//   z=0 -> Qb [N][PROJ] (pre-scaled by -log2e), z=1 -> Kb, z=2 -> Vt [H][64][N]
// ---------------------------------------------------------------------------
__global__ __launch_bounds__(256) void proj_mfma_kernel(
    const ushort_t* __restrict__ Xa, const ushort_t* __restrict__ Wp,
    const float* __restrict__ bq, const float* __restrict__ bk,
    const float* __restrict__ bv,
    ushort_t* __restrict__ Qb, ushort_t* __restrict__ Kb,
    ushort_t* __restrict__ Vt)
{
    const int z = blockIdx.z;
    const float* bias = (z == 0) ? bq : (z == 1) ? bk : bv;
    const float bscale = (z == 0) ? NLOG2E : 1.0f;
    const int c0 = blockIdx.x * 64;
    const int n0 = blockIdx.y * 64;

    const int tid = threadIdx.x;
    const int w = tid >> 6;
    const int lane = tid & 63;
    const int l15 = lane & 15;
    const int quad = lane >> 4;

    __shared__ ushort_t Ws[2 * 2048];  // [buf][colgroup f][lane*8] (8 KB)
    __shared__ ushort_t Es[64 * 68];   // epilogue transpose tile (8.7 KB)

    // X fragments: per-wave private, straight from global (L2-hot, read once)
    const ushort_t* xa = Xa + (size_t)(blockIdx.y * 4 + w) * 4096 + lane * 8;
    // W DMA source: wave w stages col-group w's k8-slice
    const ushort_t* wsrc = Wp + (size_t)z * 131072 * 8 +
                           (size_t)(blockIdx.x * 4 + w) * 4096 + lane * 8;

    f32x4 acc[4] = {{0.f, 0.f, 0.f, 0.f}, {0.f, 0.f, 0.f, 0.f},
                    {0.f, 0.f, 0.f, 0.f}, {0.f, 0.f, 0.f, 0.f}};

    // prologue: stage k8=0 slice -> buf0
    gld_lds16(wsrc, &Ws[w * 512]);

#pragma unroll
    for (int k8 = 0; k8 < 8; ++k8) {
        const int bo = (k8 & 1) * 2048;
        __syncthreads();               // vmcnt(0)+barrier: buf[k8&1] ready,
                                       // all waves done with buf[k8^1]
        if (k8 < 7)
            gld_lds16(wsrc + (k8 + 1) * 512,
                      &Ws[((k8 + 1) & 1) * 2048 + w * 512]);
        bf16x8 a = *(const bf16x8*)(xa + k8 * 512);
#pragma unroll
        for (int f = 0; f < 4; ++f) {
            bf16x8 b = *(const bf16x8*)&Ws[bo + f * 512 + lane * 8];
            acc[f] = __builtin_amdgcn_mfma_f32_16x16x32_bf16(a, b, acc[f], 0, 0, 0);
        }
    }

    // bias + bf16 round into LDS (layout depends on z), then coalesced store
    if (z < 2) {
        // Es[tok][c]
#pragma unroll
        for (int f = 0; f < 4; ++f) {
            const float bb = bias[c0 + f * 16 + l15] * bscale;
#pragma unroll
            for (int r = 0; r < 4; ++r)
                Es[(w * 16 + quad * 4 + r) * 68 + f * 16 + l15] = bf16rne(acc[f][r] + bb);
        }
    } else {
        // Es[c][tok]
#pragma unroll
        for (int f = 0; f < 4; ++f) {
            const float bb = bias[c0 + f * 16 + l15];
#pragma unroll
            for (int r = 0; r < 4; ++r)
                Es[(f * 16 + l15) * 68 + w * 16 + quad * 4 + r] = bf16rne(acc[f][r] + bb);
        }
    }
    __syncthreads();

    const int erow = tid >> 2;            // 0..63
    const int ecol = (tid & 3) * 16;      // 0,16,32,48 (+8 second store)
    uint4 pk0 = *(uint4*)&Es[erow * 68 + ecol];
    uint4 pk1 = *(uint4*)&Es[erow * 68 + ecol + 8];
    if (z < 2) {
        ushort_t* out = z ? Kb : Qb;
        ushort_t* p = &out[(size_t)(n0 + erow) * PROJ + c0 + ecol];
        *(uint4*)p = pk0;
        *(uint4*)(p + 8) = pk1;
    } else {
        ushort_t* p = &Vt[(size_t)(c0 + erow) * N_TOK + n0 + ecol];
        *(uint4*)p = pk0;
        *(uint4*)(p + 8) = pk1;
    }
}

// ---------------------------------------------------------------------------
// Kernel 2 (R10 = R7's proven version, byte-identical): fused sigmoid
// attention, bf16 MFMA 32x32x16.  global_load_lds K/V staging (swizzle on
// global source), double-buffered, one barrier/tile; Ps-LDS-free softmax
// (T12 cvt_pk + permlane32_swap, R5-verified pairing); 32-key
// half-pipelines with p[16] softmax (R7 form — SIGPK retired, see above).
// block 256 (4 waves x 32 q), grid (32, 8, ZS=4) = 1024 = 4/CU.
// ---------------------------------------------------------------------------
template<int ZS>
__global__ __launch_bounds__(256, 4) void attn_kernel(
    const ushort_t* __restrict__ Qb, const ushort_t* __restrict__ Kb,
    const ushort_t* __restrict__ Vt,
    float* __restrict__ NUM, float* __restrict__ DEN)
{
    constexpr int KEYS = N_TOK / ZS;      // keys per block
    constexpr int TILES = KEYS / 64;      // 64-key tiles per block

    const int h = blockIdx.y;
    const int z = blockIdx.z;
    const int n0 = blockIdx.x * 128;
    const int tid = threadIdx.x;
    const int w = tid >> 6;               // 0..3, wave owns queries w*32..+31
    const int lane = tid & 63;
    const int l31 = lane & 31;
    const int hf = lane >> 5;             // half-wave: k-chunk select

    __shared__ ushort_t Ks[2 * 64 * 64];  // [buf][key][d], xor-swizzled chunks
    __shared__ ushort_t Vs[2 * 64 * 64];  // [buf][d][key], xor-swizzled chunks

    // Q B-fragments, register-resident (pre-scaled by -log2e).
    bf16x8 qb[4];
    {
        const ushort_t* base = Qb + (size_t)(n0 + w * 32 + l31) * PROJ + h * 64 + hf * 8;
        qb[0] = *(const bf16x8*)(base);
        qb[1] = *(const bf16x8*)(base + 16);
        qb[2] = *(const bf16x8*)(base + 32);
        qb[3] = *(const bf16x8*)(base + 48);
    }

    f32x16 o0 = {};                       // O[q][d: 0..31]
    f32x16 o1 = {};                       // O[q][d: 32..63]
    float den = 0.0f;                     // per-lane partial DEN

    // DMA staging geometry: wave w covers rows w*16..w*16+15 in two issues
    // of 8 rows; lane -> (row = r0 + (lane>>3), physical chunk = lane&7).
    // Global source fetches logical chunk pc ^ (row&7) = pc ^ lrow.
    const int lrow = lane >> 3;
    const int pc = lane & 7;
    const int swz = (pc ^ lrow) * 8;      // shorts
    const int lb = w * 1024;              // wave's LDS base (shorts)
    const ushort_t* kg = Kb + (size_t)h * 64 +
                         ((size_t)z * KEYS + w * 16 + lrow) * PROJ + swz;
    const ushort_t* vg = Vt + ((size_t)h * 64 + w * 16 + lrow) * N_TOK +
                         (size_t)z * KEYS + swz;

    const int xm = l31 & 7;               // fragment-read swizzle mask

    // prologue: stage tile 0 -> buf 0 (drained by first loop barrier)
    gld_lds16(kg,             &Ks[lb]);
    gld_lds16(kg + 8 * PROJ,  &Ks[lb + 512]);
    gld_lds16(vg,             &Vs[lb]);
    gld_lds16(vg + 8 * N_TOK, &Vs[lb + 512]);
    kg += 64 * PROJ;
    vg += 64;

    for (int lt = 0; lt < TILES; ++lt) {
        const int bo = (lt & 1) << 12;    // read-buffer offset (shorts)
        __syncthreads();                  // vmcnt(0)+barrier: buf[lt&1] ready,
                                          // all waves done with buf[lt^1]
        if (lt + 1 < TILES) {             // DMA tile lt+1 into other buffer
            const int bw = ((lt + 1) & 1) << 12;
            gld_lds16(kg,             &Ks[bw + lb]);
            gld_lds16(kg + 8 * PROJ,  &Ks[bw + lb + 512]);
            gld_lds16(vg,             &Vs[bw + lb]);
            gld_lds16(vg + 8 * N_TOK, &Vs[bw + lb + 512]);
            kg += 64 * PROJ;
            vg += 64;
        }

        // ================= half A: keys 0-31 =================
        {
            f32x16 s0 = {};
            __builtin_amdgcn_s_setprio(1);
#pragma unroll
            for (int ks = 0; ks < 4; ++ks) {
                const int pos = ((ks * 2 + hf) ^ xm) * 8;
                bf16x8 ka = *(const bf16x8*)&Ks[bo + l31 * 64 + pos];
                s0 = __builtin_amdgcn_mfma_f32_32x32x16_bf16(ka, qb[ks], s0, 0, 0, 0);
            }
            __builtin_amdgcn_s_setprio(0);

            float p[16];
#pragma unroll
            for (int r = 0; r < 16; ++r) {
                p[r] = __builtin_amdgcn_rcpf(1.0f + __builtin_amdgcn_exp2f(s0[r]));
                den += p[r];
            }
            unsigned d00 = cvtpk_bf16(p[0],  p[1]);
            unsigned d01 = cvtpk_bf16(p[2],  p[3]);
            unsigned d10 = cvtpk_bf16(p[4],  p[5]);
            unsigned d11 = cvtpk_bf16(p[6],  p[7]);
            unsigned d20 = cvtpk_bf16(p[8],  p[9]);
            unsigned d21 = cvtpk_bf16(p[10], p[11]);
            unsigned d30 = cvtpk_bf16(p[12], p[13]);
            unsigned d31 = cvtpk_bf16(p[14], p[15]);
            PLSWAP(d00, d10);
            PLSWAP(d01, d11);
            PLSWAP(d20, d30);
            PLSWAP(d21, d31);
            union { unsigned u[4]; bf16x8 v; } A0, A1;
            A0.u[0] = d00; A0.u[1] = d01; A0.u[2] = d10; A0.u[3] = d11;
            A1.u[0] = d20; A1.u[1] = d21; A1.u[2] = d30; A1.u[3] = d31;

            __builtin_amdgcn_s_setprio(1);
            {
                const int pos = ((0 + hf) ^ xm) * 8;          // ks=0
                bf16x8 vb0 = *(const bf16x8*)&Vs[bo + l31 * 64 + pos];
                o0 = __builtin_amdgcn_mfma_f32_32x32x16_bf16(A0.v, vb0, o0, 0, 0, 0);
                bf16x8 vb1 = *(const bf16x8*)&Vs[bo + (32 + l31) * 64 + pos];
                o1 = __builtin_amdgcn_mfma_f32_32x32x16_bf16(A0.v, vb1, o1, 0, 0, 0);
            }
            {
                const int pos = ((2 + hf) ^ xm) * 8;          // ks=1
                bf16x8 vb0 = *(const bf16x8*)&Vs[bo + l31 * 64 + pos];
                o0 = __builtin_amdgcn_mfma_f32_32x32x16_bf16(A1.v, vb0, o0, 0, 0, 0);
                bf16x8 vb1 = *(const bf16x8*)&Vs[bo + (32 + l31) * 64 + pos];
                o1 = __builtin_amdgcn_mfma_f32_32x32x16_bf16(A1.v, vb1, o1, 0, 0, 0);
            }
            __builtin_amdgcn_s_setprio(0);
        }

        // ================= half B: keys 32-63 =================
        {
            f32x16 s1 = {};
            __builtin_amdgcn_s_setprio(1);
#pragma unroll
            for (int ks = 0; ks < 4; ++ks) {
                const int pos = ((ks * 2 + hf) ^ xm) * 8;
                bf16x8 ka = *(const bf16x8*)&Ks[bo + (32 + l31) * 64 + pos];
                s1 = __builtin_amdgcn_mfma_f32_32x32x16_bf16(ka, qb[ks], s1, 0, 0, 0);
            }
            __builtin_amdgcn_s_setprio(0);

            float p[16];
#pragma unroll
            for (int r = 0; r < 16; ++r) {
                p[r] = __builtin_amdgcn_rcpf(1.0f + __builtin_amdgcn_exp2f(s1[r]));
                den += p[r];
            }
            unsigned e00 = cvtpk_bf16(p[0],  p[1]);
            unsigned e01 = cvtpk_bf16(p[2],  p[3]);
            unsigned e10 = cvtpk_bf16(p[4],  p[5]);
            unsigned e11 = cvtpk_bf16(p[6],  p[7]);
            unsigned e20 = cvtpk_bf16(p[8],  p[9]);
            unsigned e21 = cvtpk_bf16(p[10], p[11]);
            unsigned e30 = cvtpk_bf16(p[12], p[13]);
            unsigned e31 = cvtpk_bf16(p[14], p[15]);
            PLSWAP(e00, e10);
            PLSWAP(e01, e11);
            PLSWAP(e20, e30);
            PLSWAP(e21, e31);
            union { unsigned u[4]; bf16x8 v; } A2, A3;
            A2.u[0] = e00; A2.u[1] = e01; A2.u[2] = e10; A2.u[3] = e11;
            A3.u[0] = e20; A3.u[1] = e21; A3.u[2] = e30; A3.u[3] = e31;

            __builtin_amdgcn_s_setprio(1);
            {
                const int pos = ((4 + hf) ^ xm) * 8;          // ks=2
                bf16x8 vb0 = *(const bf16x8*)&Vs[bo + l31 * 64 + pos];
                o0 = __builtin_amdgcn_mfma_f32_32x32x16_bf16(A2.v, vb0, o0, 0, 0, 0);
                bf16x8 vb1 = *(const bf16x8*)&Vs[bo + (32 + l31) * 64 + pos];
                o1 = __builtin_amdgcn_mfma_f32_32x32x16_bf16(A2.v, vb1, o1, 0, 0, 0);
            }
            {
                const int pos = ((6 + hf) ^ xm) * 8;          // ks=3
                bf16x8 vb0 = *(const bf16x8*)&Vs[bo + l31 * 64 + pos];
                o0 = __builtin_amdgcn_mfma_f32_32x32x16_bf16(A3.v, vb0, o0, 0, 0, 0);
                bf16x8 vb1 = *(const bf16x8*)&Vs[bo + (32 + l31) * 64 + pos];
                o1 = __builtin_amdgcn_mfma_f32_32x32x16_bf16(A3.v, vb1, o1, 0, 0, 0);
            }
            __builtin_amdgcn_s_setprio(0);
        }
    }

    // epilogue: unnormalized numerator.  q-row = (reg&3) + 8*(reg>>2) + 4*hf
#pragma unroll
    for (int rq = 0; rq < 4; ++rq) {
#pragma unroll
        for (int j = 0; j < 4; ++j) {
            const int q = n0 + w * 32 + rq * 8 + hf * 4 + j;
            float* np_ = &NUM[((size_t)z * N_TOK + q) * PROJ + h * 64 + l31];
            np_[0]  = o0[rq * 4 + j];
            np_[32] = o1[rq * 4 + j];
        }
    }
    // DEN: lane's den covers 32 keys of column q = l31; partner lane^32 has
    // the complementary 32.  Sum across halves, lanes 0..31 write.
    den += __shfl_xor(den, 32);
    if (lane < 32) {
        DEN[((size_t)z * N_TOK + n0 + w * 32 + lane) * HEADS + h] = den;
    }
}

// ---------------------------------------------------------------------------
// Kernel 3: out[n][d] = (1/8) * sum_h (sum_z NUM_z)/(sum_z DEN_z)
// ---------------------------------------------------------------------------
template<int ZS>
__global__ __launch_bounds__(256) void reduce_kernel(
    const float* __restrict__ NUM, const float* __restrict__ DEN,
    float* __restrict__ out)
{
    const int g = blockIdx.x * 256 + threadIdx.x;
    const int n = g >> 6;
    const int d = g & 63;
    float acc = 0.0f;
#pragma unroll
    for (int hh = 0; hh < HEADS; ++hh) {
        float num = 0.0f, dd = 0.0f;
#pragma unroll
        for (int zz = 0; zz < ZS; ++zz) {
            num += NUM[((size_t)zz * N_TOK + n) * PROJ + hh * 64 + d];
            dd  += DEN[((size_t)zz * N_TOK + n) * HEADS + hh];
        }
        acc += num / dd;
    }
    out[g] = acc * 0.125f;
}

extern "C" void kernel_launch(void* const* d_in, const int* in_sizes, int n_in,
                              void* d_out, int out_size, void* d_ws, size_t ws_size,
                              hipStream_t stream) {
    (void)in_sizes; (void)n_in; (void)out_size;
    const float* X  = (const float*)d_in[0];
    const float* Wq = (const float*)d_in[1];
    const float* bq = (const float*)d_in[2];
    const float* Wk = (const float*)d_in[3];
    const float* bk = (const float*)d_in[4];
    const float* Wv = (const float*)d_in[5];
    const float* bv = (const float*)d_in[6];
    float* out = (float*)d_out;

    // ws need at ZS=4: 33.55M (NUM) + 0.52M (DEN) + 12.58M (Qb/Kb/Vt)
    //                + 2.10M (Xa) + 0.79M (Wp) = 49.55 MB.  Fallback ZS=2.
    const size_t NEED4 =
        (size_t)4 * N_TOK * PROJ * 4 + (size_t)4 * N_TOK * HEADS * 4 +
        (size_t)3 * N_TOK * PROJ * 2 + (size_t)N_TOK * IN_CH * 2 +
        (size_t)3 * PROJ * IN_CH * 2;
    const int ZS = (ws_size >= NEED4) ? 4 : 2;

    float* NUM = (float*)d_ws;                              // [ZS][N][PROJ] f32
    float* DEN = NUM + (size_t)ZS * N_TOK * PROJ;           // [ZS][N][HEADS] f32
    ushort_t* Qb = (ushort_t*)(DEN + (size_t)ZS * N_TOK * HEADS);
    ushort_t* Kb = Qb + (size_t)N_TOK * PROJ;
    ushort_t* Vt = Kb + (size_t)N_TOK * PROJ;               // [H][64][N]
    ushort_t* Xa = Vt + (size_t)N_TOK * PROJ;               // frag-packed X
    ushort_t* Wp = Xa + (size_t)N_TOK * IN_CH;              // frag-packed W x3

    cast_pack_kernel<<<dim3(704), 256, 0, stream>>>(X, Wq, Wk, Wv, Xa, Wp);
    proj_mfma_kernel<<<dim3(PROJ / 64, N_TOK / 64, 3), 256, 0, stream>>>(
        Xa, Wp, bq, bk, bv, Qb, Kb, Vt);
    if (ZS == 4) {
        attn_kernel<4><<<dim3(N_TOK / 128, HEADS, 4), 256, 0, stream>>>(
            Qb, Kb, Vt, NUM, DEN);
        reduce_kernel<4><<<dim3(N_TOK * OUT_CH / 256), 256, 0, stream>>>(
            NUM, DEN, out);
    } else {
        attn_kernel<2><<<dim3(N_TOK / 128, HEADS, 2), 256, 0, stream>>>(
            Qb, Kb, Vt, NUM, DEN);
        reduce_kernel<2><<<dim3(N_TOK * OUT_CH / 256), 256, 0, stream>>>(
            NUM, DEN, out);
    }
}

// Round 11
// 136.881 us; speedup vs baseline: 1.3404x; 1.0152x over previous
//
#include <hip/hip_runtime.h>
#include <hip/hip_bf16.h>
#include <math.h>

#define N_TOK 4096
#define IN_CH 256
#define OUT_CH 64
#define HEADS 8
#define PROJ (OUT_CH * HEADS) /* 512 */
#define NLOG2E -1.44269504088896340736f

typedef float f32x4 __attribute__((ext_vector_type(4)));
typedef float f32x16 __attribute__((ext_vector_type(16)));
typedef __bf16 bf16x8 __attribute__((ext_vector_type(8)));
typedef unsigned short ushort_t;

__device__ inline ushort_t bf16rne(float x) {
    unsigned u = __float_as_uint(x);
    unsigned r = (u + 0x7FFFu + ((u >> 16) & 1u)) >> 16;
    return (ushort_t)r;
}

// packed f32->bf16x2 convert (RNE): D[15:0]=bf16(lo), D[31:16]=bf16(hi).
__device__ inline unsigned cvtpk_bf16(float lo, float hi) {
    unsigned d;
    asm("v_cvt_pk_bf16_f32 %0, %1, %2" : "=v"(d) : "v"(lo), "v"(hi));
    return d;
}
// v_permlane32_swap_b32 VDST, VSRC (R5-verified semantics):
// After PLSWAP(x, y):  x = {lo: own x,      hi: partner y}
//                      y = {lo: partner x,  hi: own y}
#define PLSWAP(x, y) asm("v_permlane32_swap_b32 %0, %1" : "+v"(x), "+v"(y))

// NOTE: the SIGPK fused-softmax macro remains RETIRED (R8/R9 bit-identical
// miscompile at absmax 860.033; R10 isolated it).  Softmax stays in the
// p[16] form below.

// async global->LDS DMA, 16B per lane.  LDS dest = wave-uniform base +
// lane*16; swizzle achieved by pre-swizzling the per-lane GLOBAL address.
__device__ inline void gld_lds16(const ushort_t* g, ushort_t* l) {
    __builtin_amdgcn_global_load_lds(
        (const __attribute__((address_space(1))) unsigned int*)g,
        (__attribute__((address_space(3))) unsigned int*)l,
        16, 0, 0);
}

// ---------------------------------------------------------------------------
// Kernel 0: cast X / Wq / Wk / Wv to bf16 AND pre-permute into MFMA fragment
// order:  flat index (((g*8 + k8)*4 + quad)*16 + t)*8  (g = 16-row group).
// Wq additionally scaled by -log2(e) so sigmoid = rcp(1 + exp2(t)).
// ---------------------------------------------------------------------------
__global__ __launch_bounds__(256) void cast_pack_kernel(
    const float* __restrict__ X,
    const float* __restrict__ Wq, const float* __restrict__ Wk,
    const float* __restrict__ Wv,
    ushort_t* __restrict__ Xa, ushort_t* __restrict__ Wp)
{
    const int i = blockIdx.x * 256 + threadIdx.x;
    const float* src;
    ushort_t* dst;
    float scale = 1.0f;
    if (i < 131072) {                       // X part: N*IN_CH/8 packs
        const int t = i & 15, quad = (i >> 4) & 3, k8 = (i >> 6) & 7, g = i >> 9;
        src = X + (size_t)(g * 16 + t) * IN_CH + k8 * 32 + quad * 8;
        dst = Xa + (size_t)i * 8;
    } else {                                // W part: 3*PROJ*IN_CH/8 packs
        const int j = i - 131072;
        const int z = j >> 14;
        const int r = j & 16383;
        const int cl = r & 15, quad = (r >> 4) & 3, k8 = (r >> 6) & 7, gc = r >> 9;
        const float* W = (z == 0) ? Wq : (z == 1) ? Wk : Wv;
        src = W + (size_t)(gc * 16 + cl) * IN_CH + k8 * 32 + quad * 8;
        dst = Wp + (size_t)z * 131072 * 8 + (size_t)r * 8;
        if (z == 0) scale = NLOG2E;
    }
    float4 a = *(const float4*)src;
    float4 b = *(const float4*)(src + 4);
    ushort_t pk[8];
    pk[0] = bf16rne(a.x * scale); pk[1] = bf16rne(a.y * scale);
    pk[2] = bf16rne(a.z * scale); pk[3] = bf16rne(a.w * scale);
    pk[4] = bf16rne(b.x * scale); pk[5] = bf16rne(b.y * scale);
    pk[6] = bf16rne(b.z * scale); pk[7] = bf16rne(b.w * scale);
    *(uint4*)dst = *(uint4*)pk;
}

// ---------------------------------------------------------------------------
// Kernel 1 (R10-proven DMA version): Q/K/V projections via bf16 MFMA.
// grid (PROJ/64, N/64, 3), block 256 (4 waves).  Wave w: 16 tokens x 64 cols.
// W staged through LDS via global_load_lds DMA, double-buffered per
// k8-slice.  Global traffic/block: 160 -> 64 KB; b-operand L2 -> LDS.
// Epilogue: LDS transpose so all global stores are uint4.
//   z=0 -> Qb [N][PROJ] (pre-scaled by -log2e), z=1 -> Kb, z=2 -> Vt [H][64][N]
// ---------------------------------------------------------------------------
__global__ __launch_bounds__(256) void proj_mfma_kernel(
    const ushort_t* __restrict__ Xa, const ushort_t* __restrict__ Wp,
    const float* __restrict__ bq, const float* __restrict__ bk,
    const float* __restrict__ bv,
    ushort_t* __restrict__ Qb, ushort_t* __restrict__ Kb,
    ushort_t* __restrict__ Vt)
{
    const int z = blockIdx.z;
    const float* bias = (z == 0) ? bq : (z == 1) ? bk : bv;
    const float bscale = (z == 0) ? NLOG2E : 1.0f;
    const int c0 = blockIdx.x * 64;
    const int n0 = blockIdx.y * 64;

    const int tid = threadIdx.x;
    const int w = tid >> 6;
    const int lane = tid & 63;
    const int l15 = lane & 15;
    const int quad = lane >> 4;

    __shared__ ushort_t Ws[2 * 2048];  // [buf][colgroup f][lane*8] (8 KB)
    __shared__ ushort_t Es[64 * 68];   // epilogue transpose tile (8.7 KB)

    // X fragments: per-wave private, straight from global (L2-hot, read once)
    const ushort_t* xa = Xa + (size_t)(blockIdx.y * 4 + w) * 4096 + lane * 8;
    // W DMA source: wave w stages col-group w's k8-slice
    const ushort_t* wsrc = Wp + (size_t)z * 131072 * 8 +
                           (size_t)(blockIdx.x * 4 + w) * 4096 + lane * 8;

    f32x4 acc[4] = {{0.f, 0.f, 0.f, 0.f}, {0.f, 0.f, 0.f, 0.f},
                    {0.f, 0.f, 0.f, 0.f}, {0.f, 0.f, 0.f, 0.f}};

    // prologue: stage k8=0 slice -> buf0
    gld_lds16(wsrc, &Ws[w * 512]);

#pragma unroll
    for (int k8 = 0; k8 < 8; ++k8) {
        const int bo = (k8 & 1) * 2048;
        __syncthreads();               // vmcnt(0)+barrier: buf[k8&1] ready,
                                       // all waves done with buf[k8^1]
        if (k8 < 7)
            gld_lds16(wsrc + (k8 + 1) * 512,
                      &Ws[((k8 + 1) & 1) * 2048 + w * 512]);
        bf16x8 a = *(const bf16x8*)(xa + k8 * 512);
#pragma unroll
        for (int f = 0; f < 4; ++f) {
            bf16x8 b = *(const bf16x8*)&Ws[bo + f * 512 + lane * 8];
            acc[f] = __builtin_amdgcn_mfma_f32_16x16x32_bf16(a, b, acc[f], 0, 0, 0);
        }
    }

    // bias + bf16 round into LDS (layout depends on z), then coalesced store
    if (z < 2) {
        // Es[tok][c]
#pragma unroll
        for (int f = 0; f < 4; ++f) {
            const float bb = bias[c0 + f * 16 + l15] * bscale;
#pragma unroll
            for (int r = 0; r < 4; ++r)
                Es[(w * 16 + quad * 4 + r) * 68 + f * 16 + l15] = bf16rne(acc[f][r] + bb);
        }
    } else {
        // Es[c][tok]
#pragma unroll
        for (int f = 0; f < 4; ++f) {
            const float bb = bias[c0 + f * 16 + l15];
#pragma unroll
            for (int r = 0; r < 4; ++r)
                Es[(f * 16 + l15) * 68 + w * 16 + quad * 4 + r] = bf16rne(acc[f][r] + bb);
        }
    }
    __syncthreads();

    const int erow = tid >> 2;            // 0..63
    const int ecol = (tid & 3) * 16;      // 0,16,32,48 (+8 second store)
    uint4 pk0 = *(uint4*)&Es[erow * 68 + ecol];
    uint4 pk1 = *(uint4*)&Es[erow * 68 + ecol + 8];
    if (z < 2) {
        ushort_t* out = z ? Kb : Qb;
        ushort_t* p = &out[(size_t)(n0 + erow) * PROJ + c0 + ecol];
        *(uint4*)p = pk0;
        *(uint4*)(p + 8) = pk1;
    } else {
        ushort_t* p = &Vt[(size_t)(c0 + erow) * N_TOK + n0 + ecol];
        *(uint4*)p = pk0;
        *(uint4*)(p + 8) = pk1;
    }
}

// ---------------------------------------------------------------------------
// Kernel 2 (R11): fused sigmoid attention, bf16 MFMA 32x32x16.
// Carried from R10 (proven): global_load_lds K/V staging, double-buffered,
// one barrier/tile; Ps-LDS-free softmax (T12 cvt_pk + permlane32_swap);
// 32-key half-pipelines with p[16] softmax.
// R11 delta (single change): DEN moved from VALU adds to the MFMA pipe via
// a ones-B fragment (mechanism proven in R0-R2).  The P A-frags are already
// in registers, so the old cost (Ps LDS reads) is gone.  Removes 32 VALU
// adds per lane per tile (~6.8 us/CU of VALU, the busiest pipe at 53%);
// adds 4 MFMAs/wave-tile on the 24%-busy matrix pipe.  dacc (16 AGPRs)
// brings the accumulator bank to exactly 64: o(32) + s(16 transient) +
// dacc(16).  DEN epilogue uses the HW-verified 32x32 C-map:
// q-row = (r&3) + 8*(r>>2) + 4*hf, identical across cols; lanes l31==0 of
// each half write 16 values each.
// block 256 (4 waves x 32 q), grid (32, 8, ZS=4) = 1024 = 4/CU.
// ---------------------------------------------------------------------------
template<int ZS>
__global__ __launch_bounds__(256, 4) void attn_kernel(
    const ushort_t* __restrict__ Qb, const ushort_t* __restrict__ Kb,
    const ushort_t* __restrict__ Vt,
    float* __restrict__ NUM, float* __restrict__ DEN)
{
    constexpr int KEYS = N_TOK / ZS;      // keys per block
    constexpr int TILES = KEYS / 64;      // 64-key tiles per block

    const int h = blockIdx.y;
    const int z = blockIdx.z;
    const int n0 = blockIdx.x * 128;
    const int tid = threadIdx.x;
    const int w = tid >> 6;               // 0..3, wave owns queries w*32..+31
    const int lane = tid & 63;
    const int l31 = lane & 31;
    const int hf = lane >> 5;             // half-wave: k-chunk select

    __shared__ ushort_t Ks[2 * 64 * 64];  // [buf][key][d], xor-swizzled chunks
    __shared__ ushort_t Vs[2 * 64 * 64];  // [buf][d][key], xor-swizzled chunks

    // Q B-fragments, register-resident (pre-scaled by -log2e).
    bf16x8 qb[4];
    {
        const ushort_t* base = Qb + (size_t)(n0 + w * 32 + l31) * PROJ + h * 64 + hf * 8;
        qb[0] = *(const bf16x8*)(base);
        qb[1] = *(const bf16x8*)(base + 16);
        qb[2] = *(const bf16x8*)(base + 32);
        qb[3] = *(const bf16x8*)(base + 48);
    }

    bf16x8 onesv;
#pragma unroll
    for (int j = 0; j < 8; ++j) onesv[j] = (__bf16)1.0f;

    f32x16 o0 = {};                       // O[q][d: 0..31]
    f32x16 o1 = {};                       // O[q][d: 32..63]
    f32x16 dacc = {};                     // DEN via MFMA-ones (R0-R2 proven)

    // DMA staging geometry: wave w covers rows w*16..w*16+15 in two issues
    // of 8 rows; lane -> (row = r0 + (lane>>3), physical chunk = lane&7).
    // Global source fetches logical chunk pc ^ (row&7) = pc ^ lrow.
    const int lrow = lane >> 3;
    const int pc = lane & 7;
    const int swz = (pc ^ lrow) * 8;      // shorts
    const int lb = w * 1024;              // wave's LDS base (shorts)
    const ushort_t* kg = Kb + (size_t)h * 64 +
                         ((size_t)z * KEYS + w * 16 + lrow) * PROJ + swz;
    const ushort_t* vg = Vt + ((size_t)h * 64 + w * 16 + lrow) * N_TOK +
                         (size_t)z * KEYS + swz;

    const int xm = l31 & 7;               // fragment-read swizzle mask

    // prologue: stage tile 0 -> buf 0 (drained by first loop barrier)
    gld_lds16(kg,             &Ks[lb]);
    gld_lds16(kg + 8 * PROJ,  &Ks[lb + 512]);
    gld_lds16(vg,             &Vs[lb]);
    gld_lds16(vg + 8 * N_TOK, &Vs[lb + 512]);
    kg += 64 * PROJ;
    vg += 64;

    for (int lt = 0; lt < TILES; ++lt) {
        const int bo = (lt & 1) << 12;    // read-buffer offset (shorts)
        __syncthreads();                  // vmcnt(0)+barrier: buf[lt&1] ready,
                                          // all waves done with buf[lt^1]
        if (lt + 1 < TILES) {             // DMA tile lt+1 into other buffer
            const int bw = ((lt + 1) & 1) << 12;
            gld_lds16(kg,             &Ks[bw + lb]);
            gld_lds16(kg + 8 * PROJ,  &Ks[bw + lb + 512]);
            gld_lds16(vg,             &Vs[bw + lb]);
            gld_lds16(vg + 8 * N_TOK, &Vs[bw + lb + 512]);
            kg += 64 * PROJ;
            vg += 64;
        }

        // ================= half A: keys 0-31 =================
        {
            f32x16 s0 = {};
            __builtin_amdgcn_s_setprio(1);
#pragma unroll
            for (int ks = 0; ks < 4; ++ks) {
                const int pos = ((ks * 2 + hf) ^ xm) * 8;
                bf16x8 ka = *(const bf16x8*)&Ks[bo + l31 * 64 + pos];
                s0 = __builtin_amdgcn_mfma_f32_32x32x16_bf16(ka, qb[ks], s0, 0, 0, 0);
            }
            __builtin_amdgcn_s_setprio(0);

            float p[16];
#pragma unroll
            for (int r = 0; r < 16; ++r) {
                p[r] = __builtin_amdgcn_rcpf(1.0f + __builtin_amdgcn_exp2f(s0[r]));
            }
            unsigned d00 = cvtpk_bf16(p[0],  p[1]);
            unsigned d01 = cvtpk_bf16(p[2],  p[3]);
            unsigned d10 = cvtpk_bf16(p[4],  p[5]);
            unsigned d11 = cvtpk_bf16(p[6],  p[7]);
            unsigned d20 = cvtpk_bf16(p[8],  p[9]);
            unsigned d21 = cvtpk_bf16(p[10], p[11]);
            unsigned d30 = cvtpk_bf16(p[12], p[13]);
            unsigned d31 = cvtpk_bf16(p[14], p[15]);
            PLSWAP(d00, d10);
            PLSWAP(d01, d11);
            PLSWAP(d20, d30);
            PLSWAP(d21, d31);
            union { unsigned u[4]; bf16x8 v; } A0, A1;
            A0.u[0] = d00; A0.u[1] = d01; A0.u[2] = d10; A0.u[3] = d11;
            A1.u[0] = d20; A1.u[1] = d21; A1.u[2] = d30; A1.u[3] = d31;

            __builtin_amdgcn_s_setprio(1);
            {
                const int pos = ((0 + hf) ^ xm) * 8;          // ks=0
                bf16x8 vb0 = *(const bf16x8*)&Vs[bo + l31 * 64 + pos];
                o0 = __builtin_amdgcn_mfma_f32_32x32x16_bf16(A0.v, vb0, o0, 0, 0, 0);
                bf16x8 vb1 = *(const bf16x8*)&Vs[bo + (32 + l31) * 64 + pos];
                o1 = __builtin_amdgcn_mfma_f32_32x32x16_bf16(A0.v, vb1, o1, 0, 0, 0);
            }
            dacc = __builtin_amdgcn_mfma_f32_32x32x16_bf16(A0.v, onesv, dacc, 0, 0, 0);
            {
                const int pos = ((2 + hf) ^ xm) * 8;          // ks=1
                bf16x8 vb0 = *(const bf16x8*)&Vs[bo + l31 * 64 + pos];
                o0 = __builtin_amdgcn_mfma_f32_32x32x16_bf16(A1.v, vb0, o0, 0, 0, 0);
                bf16x8 vb1 = *(const bf16x8*)&Vs[bo + (32 + l31) * 64 + pos];
                o1 = __builtin_amdgcn_mfma_f32_32x32x16_bf16(A1.v, vb1, o1, 0, 0, 0);
            }
            dacc = __builtin_amdgcn_mfma_f32_32x32x16_bf16(A1.v, onesv, dacc, 0, 0, 0);
            __builtin_amdgcn_s_setprio(0);
        }

        // ================= half B: keys 32-63 =================
        {
            f32x16 s1 = {};
            __builtin_amdgcn_s_setprio(1);
#pragma unroll
            for (int ks = 0; ks < 4; ++ks) {
                const int pos = ((ks * 2 + hf) ^ xm) * 8;
                bf16x8 ka = *(const bf16x8*)&Ks[bo + (32 + l31) * 64 + pos];
                s1 = __builtin_amdgcn_mfma_f32_32x32x16_bf16(ka, qb[ks], s1, 0, 0, 0);
            }
            __builtin_amdgcn_s_setprio(0);

            float p[16];
#pragma unroll
            for (int r = 0; r < 16; ++r) {
                p[r] = __builtin_amdgcn_rcpf(1.0f + __builtin_amdgcn_exp2f(s1[r]));
            }
            unsigned e00 = cvtpk_bf16(p[0],  p[1]);
            unsigned e01 = cvtpk_bf16(p[2],  p[3]);
            unsigned e10 = cvtpk_bf16(p[4],  p[5]);
            unsigned e11 = cvtpk_bf16(p[6],  p[7]);
            unsigned e20 = cvtpk_bf16(p[8],  p[9]);
            unsigned e21 = cvtpk_bf16(p[10], p[11]);
            unsigned e30 = cvtpk_bf16(p[12], p[13]);
            unsigned e31 = cvtpk_bf16(p[14], p[15]);
            PLSWAP(e00, e10);
            PLSWAP(e01, e11);
            PLSWAP(e20, e30);
            PLSWAP(e21, e31);
            union { unsigned u[4]; bf16x8 v; } A2, A3;
            A2.u[0] = e00; A2.u[1] = e01; A2.u[2] = e10; A2.u[3] = e11;
            A3.u[0] = e20; A3.u[1] = e21; A3.u[2] = e30; A3.u[3] = e31;

            __builtin_amdgcn_s_setprio(1);
            {
                const int pos = ((4 + hf) ^ xm) * 8;          // ks=2
                bf16x8 vb0 = *(const bf16x8*)&Vs[bo + l31 * 64 + pos];
                o0 = __builtin_amdgcn_mfma_f32_32x32x16_bf16(A2.v, vb0, o0, 0, 0, 0);
                bf16x8 vb1 = *(const bf16x8*)&Vs[bo + (32 + l31) * 64 + pos];
                o1 = __builtin_amdgcn_mfma_f32_32x32x16_bf16(A2.v, vb1, o1, 0, 0, 0);
            }
            dacc = __builtin_amdgcn_mfma_f32_32x32x16_bf16(A2.v, onesv, dacc, 0, 0, 0);
            {
                const int pos = ((6 + hf) ^ xm) * 8;          // ks=3
                bf16x8 vb0 = *(const bf16x8*)&Vs[bo + l31 * 64 + pos];
                o0 = __builtin_amdgcn_mfma_f32_32x32x16_bf16(A3.v, vb0, o0, 0, 0, 0);
                bf16x8 vb1 = *(const bf16x8*)&Vs[bo + (32 + l31) * 64 + pos];
                o1 = __builtin_amdgcn_mfma_f32_32x32x16_bf16(A3.v, vb1, o1, 0, 0, 0);
            }
            dacc = __builtin_amdgcn_mfma_f32_32x32x16_bf16(A3.v, onesv, dacc, 0, 0, 0);
            __builtin_amdgcn_s_setprio(0);
        }
    }

    // epilogue: unnormalized numerator.  q-row = (reg&3) + 8*(reg>>2) + 4*hf
#pragma unroll
    for (int rq = 0; rq < 4; ++rq) {
#pragma unroll
        for (int j = 0; j < 4; ++j) {
            const int q = n0 + w * 32 + rq * 8 + hf * 4 + j;
            float* np_ = &NUM[((size_t)z * N_TOK + q) * PROJ + h * 64 + l31];
            np_[0]  = o0[rq * 4 + j];
            np_[32] = o1[rq * 4 + j];
        }
    }
    // DEN from dacc: D[q][c] = sum_k P[q][k]*1, identical across cols c.
    // Lane col l31==0 of each half writes its 16 q-rows.
    if (l31 == 0) {
#pragma unroll
        for (int r = 0; r < 16; ++r) {
            const int q = n0 + w * 32 + (r & 3) + 8 * (r >> 2) + 4 * hf;
            DEN[((size_t)z * N_TOK + q) * HEADS + h] = dacc[r];
        }
    }
}

// ---------------------------------------------------------------------------
// Kernel 3: out[n][d] = (1/8) * sum_h (sum_z NUM_z)/(sum_z DEN_z)
// ---------------------------------------------------------------------------
template<int ZS>
__global__ __launch_bounds__(256) void reduce_kernel(
    const float* __restrict__ NUM, const float* __restrict__ DEN,
    float* __restrict__ out)
{
    const int g = blockIdx.x * 256 + threadIdx.x;
    const int n = g >> 6;
    const int d = g & 63;
    float acc = 0.0f;
#pragma unroll
    for (int hh = 0; hh < HEADS; ++hh) {
        float num = 0.0f, dd = 0.0f;
#pragma unroll
        for (int zz = 0; zz < ZS; ++zz) {
            num += NUM[((size_t)zz * N_TOK + n) * PROJ + hh * 64 + d];
            dd  += DEN[((size_t)zz * N_TOK + n) * HEADS + hh];
        }
        acc += num / dd;
    }
    out[g] = acc * 0.125f;
}

extern "C" void kernel_launch(void* const* d_in, const int* in_sizes, int n_in,
                              void* d_out, int out_size, void* d_ws, size_t ws_size,
                              hipStream_t stream) {
    (void)in_sizes; (void)n_in; (void)out_size;
    const float* X  = (const float*)d_in[0];
    const float* Wq = (const float*)d_in[1];
    const float* bq = (const float*)d_in[2];
    const float* Wk = (const float*)d_in[3];
    const float* bk = (const float*)d_in[4];
    const float* Wv = (const float*)d_in[5];
    const float* bv = (const float*)d_in[6];
    float* out = (float*)d_out;

    // ws need at ZS=4: 33.55M (NUM) + 0.52M (DEN) + 12.58M (Qb/Kb/Vt)
    //                + 2.10M (Xa) + 0.79M (Wp) = 49.55 MB.  Fallback ZS=2.
    const size_t NEED4 =
        (size_t)4 * N_TOK * PROJ * 4 + (size_t)4 * N_TOK * HEADS * 4 +
        (size_t)3 * N_TOK * PROJ * 2 + (size_t)N_TOK * IN_CH * 2 +
        (size_t)3 * PROJ * IN_CH * 2;
    const int ZS = (ws_size >= NEED4) ? 4 : 2;

    float* NUM = (float*)d_ws;                              // [ZS][N][PROJ] f32
    float* DEN = NUM + (size_t)ZS * N_TOK * PROJ;           // [ZS][N][HEADS] f32
    ushort_t* Qb = (ushort_t*)(DEN + (size_t)ZS * N_TOK * HEADS);
    ushort_t* Kb = Qb + (size_t)N_TOK * PROJ;
    ushort_t* Vt = Kb + (size_t)N_TOK * PROJ;               // [H][64][N]
    ushort_t* Xa = Vt + (size_t)N_TOK * PROJ;               // frag-packed X
    ushort_t* Wp = Xa + (size_t)N_TOK * IN_CH;              // frag-packed W x3

    cast_pack_kernel<<<dim3(704), 256, 0, stream>>>(X, Wq, Wk, Wv, Xa, Wp);
    proj_mfma_kernel<<<dim3(PROJ / 64, N_TOK / 64, 3), 256, 0, stream>>>(
        Xa, Wp, bq, bk, bv, Qb, Kb, Vt);
    if (ZS == 4) {
        attn_kernel<4><<<dim3(N_TOK / 128, HEADS, 4), 256, 0, stream>>>(
            Qb, Kb, Vt, NUM, DEN);
        reduce_kernel<4><<<dim3(N_TOK * OUT_CH / 256), 256, 0, stream>>>(
            NUM, DEN, out);
    } else {
        attn_kernel<2><<<dim3(N_TOK / 128, HEADS, 2), 256, 0, stream>>>(
            Qb, Kb, Vt, NUM, DEN);
        reduce_kernel<2><<<dim3(N_TOK * OUT_CH / 256), 256, 0, stream>>>(
            NUM, DEN, out);
    }
}

// Round 12
// 128.330 us; speedup vs baseline: 1.4298x; 1.0666x over previous
//
#include <hip/hip_runtime.h>
#include <hip/hip_bf16.h>
#include <math.h>

#define N_TOK 4096
#define IN_CH 256
#define OUT_CH 64
#define HEADS 8
#define PROJ (OUT_CH * HEADS) /* 512 */
#define NLOG2E -1.44269504088896340736f

typedef float f32x4 __attribute__((ext_vector_type(4)));
typedef float f32x16 __attribute__((ext_vector_type(16)));
typedef __bf16 bf16x8 __attribute__((ext_vector_type(8)));
typedef unsigned short ushort_t;
typedef _Float16 f16_t;

__device__ inline ushort_t bf16rne(float x) {
    unsigned u = __float_as_uint(x);
    unsigned r = (u + 0x7FFFu + ((u >> 16) & 1u)) >> 16;
    return (ushort_t)r;
}

// packed f32->bf16x2 convert (RNE): D[15:0]=bf16(lo), D[31:16]=bf16(hi).
__device__ inline unsigned cvtpk_bf16(float lo, float hi) {
    unsigned d;
    asm("v_cvt_pk_bf16_f32 %0, %1, %2" : "=v"(d) : "v"(lo), "v"(hi));
    return d;
}
// v_permlane32_swap_b32 VDST, VSRC (R5-verified semantics):
// After PLSWAP(x, y):  x = {lo: own x,      hi: partner y}
//                      y = {lo: partner x,  hi: own y}
#define PLSWAP(x, y) asm("v_permlane32_swap_b32 %0, %1" : "+v"(x), "+v"(y))

// NOTE: the SIGPK fused-softmax macro remains RETIRED (R8/R9 bit-identical
// miscompile at absmax 860.033; R10 isolated it).  Softmax stays in the
// p[16] form below.

// async global->LDS DMA, 16B per lane.  LDS dest = wave-uniform base +
// lane*16; swizzle achieved by pre-swizzling the per-lane GLOBAL address.
__device__ inline void gld_lds16(const ushort_t* g, ushort_t* l) {
    __builtin_amdgcn_global_load_lds(
        (const __attribute__((address_space(1))) unsigned int*)g,
        (__attribute__((address_space(3))) unsigned int*)l,
        16, 0, 0);
}

// ---------------------------------------------------------------------------
// Kernel 0: cast X / Wq / Wk / Wv to bf16 AND pre-permute into MFMA fragment
// order:  flat index (((g*8 + k8)*4 + quad)*16 + t)*8  (g = 16-row group).
// Wq additionally scaled by -log2(e) so sigmoid = rcp(1 + exp2(t)).
// ---------------------------------------------------------------------------
__global__ __launch_bounds__(256) void cast_pack_kernel(
    const float* __restrict__ X,
    const float* __restrict__ Wq, const float* __restrict__ Wk,
    const float* __restrict__ Wv,
    ushort_t* __restrict__ Xa, ushort_t* __restrict__ Wp)
{
    const int i = blockIdx.x * 256 + threadIdx.x;
    const float* src;
    ushort_t* dst;
    float scale = 1.0f;
    if (i < 131072) {                       // X part: N*IN_CH/8 packs
        const int t = i & 15, quad = (i >> 4) & 3, k8 = (i >> 6) & 7, g = i >> 9;
        src = X + (size_t)(g * 16 + t) * IN_CH + k8 * 32 + quad * 8;
        dst = Xa + (size_t)i * 8;
    } else {                                // W part: 3*PROJ*IN_CH/8 packs
        const int j = i - 131072;
        const int z = j >> 14;
        const int r = j & 16383;
        const int cl = r & 15, quad = (r >> 4) & 3, k8 = (r >> 6) & 7, gc = r >> 9;
        const float* W = (z == 0) ? Wq : (z == 1) ? Wk : Wv;
        src = W + (size_t)(gc * 16 + cl) * IN_CH + k8 * 32 + quad * 8;
        dst = Wp + (size_t)z * 131072 * 8 + (size_t)r * 8;
        if (z == 0) scale = NLOG2E;
    }
    float4 a = *(const float4*)src;
    float4 b = *(const float4*)(src + 4);
    ushort_t pk[8];
    pk[0] = bf16rne(a.x * scale); pk[1] = bf16rne(a.y * scale);
    pk[2] = bf16rne(a.z * scale); pk[3] = bf16rne(a.w * scale);
    pk[4] = bf16rne(b.x * scale); pk[5] = bf16rne(b.y * scale);
    pk[6] = bf16rne(b.z * scale); pk[7] = bf16rne(b.w * scale);
    *(uint4*)dst = *(uint4*)pk;
}

// ---------------------------------------------------------------------------
// Kernel 1 (R10-proven DMA version): Q/K/V projections via bf16 MFMA.
// grid (PROJ/64, N/64, 3), block 256 (4 waves).  Wave w: 16 tokens x 64 cols.
// W staged through LDS via global_load_lds DMA, double-buffered per
// k8-slice.  Global traffic/block: 160 -> 64 KB; b-operand L2 -> LDS.
// Epilogue: LDS transpose so all global stores are uint4.
//   z=0 -> Qb [N][PROJ] (pre-scaled by -log2e), z=1 -> Kb, z=2 -> Vt [H][64][N]
// ---------------------------------------------------------------------------
__global__ __launch_bounds__(256) void proj_mfma_kernel(
    const ushort_t* __restrict__ Xa, const ushort_t* __restrict__ Wp,
    const float* __restrict__ bq, const float* __restrict__ bk,
    const float* __restrict__ bv,
    ushort_t* __restrict__ Qb, ushort_t* __restrict__ Kb,
    ushort_t* __restrict__ Vt)
{
    const int z = blockIdx.z;
    const float* bias = (z == 0) ? bq : (z == 1) ? bk : bv;
    const float bscale = (z == 0) ? NLOG2E : 1.0f;
    const int c0 = blockIdx.x * 64;
    const int n0 = blockIdx.y * 64;

    const int tid = threadIdx.x;
    const int w = tid >> 6;
    const int lane = tid & 63;
    const int l15 = lane & 15;
    const int quad = lane >> 4;

    __shared__ ushort_t Ws[2 * 2048];  // [buf][colgroup f][lane*8] (8 KB)
    __shared__ ushort_t Es[64 * 68];   // epilogue transpose tile (8.7 KB)

    // X fragments: per-wave private, straight from global (L2-hot, read once)
    const ushort_t* xa = Xa + (size_t)(blockIdx.y * 4 + w) * 4096 + lane * 8;
    // W DMA source: wave w stages col-group w's k8-slice
    const ushort_t* wsrc = Wp + (size_t)z * 131072 * 8 +
                           (size_t)(blockIdx.x * 4 + w) * 4096 + lane * 8;

    f32x4 acc[4] = {{0.f, 0.f, 0.f, 0.f}, {0.f, 0.f, 0.f, 0.f},
                    {0.f, 0.f, 0.f, 0.f}, {0.f, 0.f, 0.f, 0.f}};

    // prologue: stage k8=0 slice -> buf0
    gld_lds16(wsrc, &Ws[w * 512]);

#pragma unroll
    for (int k8 = 0; k8 < 8; ++k8) {
        const int bo = (k8 & 1) * 2048;
        __syncthreads();               // vmcnt(0)+barrier: buf[k8&1] ready,
                                       // all waves done with buf[k8^1]
        if (k8 < 7)
            gld_lds16(wsrc + (k8 + 1) * 512,
                      &Ws[((k8 + 1) & 1) * 2048 + w * 512]);
        bf16x8 a = *(const bf16x8*)(xa + k8 * 512);
#pragma unroll
        for (int f = 0; f < 4; ++f) {
            bf16x8 b = *(const bf16x8*)&Ws[bo + f * 512 + lane * 8];
            acc[f] = __builtin_amdgcn_mfma_f32_16x16x32_bf16(a, b, acc[f], 0, 0, 0);
        }
    }

    // bias + bf16 round into LDS (layout depends on z), then coalesced store
    if (z < 2) {
        // Es[tok][c]
#pragma unroll
        for (int f = 0; f < 4; ++f) {
            const float bb = bias[c0 + f * 16 + l15] * bscale;
#pragma unroll
            for (int r = 0; r < 4; ++r)
                Es[(w * 16 + quad * 4 + r) * 68 + f * 16 + l15] = bf16rne(acc[f][r] + bb);
        }
    } else {
        // Es[c][tok]
#pragma unroll
        for (int f = 0; f < 4; ++f) {
            const float bb = bias[c0 + f * 16 + l15];
#pragma unroll
            for (int r = 0; r < 4; ++r)
                Es[(f * 16 + l15) * 68 + w * 16 + quad * 4 + r] = bf16rne(acc[f][r] + bb);
        }
    }
    __syncthreads();

    const int erow = tid >> 2;            // 0..63
    const int ecol = (tid & 3) * 16;      // 0,16,32,48 (+8 second store)
    uint4 pk0 = *(uint4*)&Es[erow * 68 + ecol];
    uint4 pk1 = *(uint4*)&Es[erow * 68 + ecol + 8];
    if (z < 2) {
        ushort_t* out = z ? Kb : Qb;
        ushort_t* p = &out[(size_t)(n0 + erow) * PROJ + c0 + ecol];
        *(uint4*)p = pk0;
        *(uint4*)(p + 8) = pk1;
    } else {
        ushort_t* p = &Vt[(size_t)(c0 + erow) * N_TOK + n0 + ecol];
        *(uint4*)p = pk0;
        *(uint4*)(p + 8) = pk1;
    }
}

// ---------------------------------------------------------------------------
// Kernel 2 (R12): fused sigmoid attention, bf16 MFMA 32x32x16.
// Carried from R11 (proven): global_load_lds K/V staging, double-buffered,
// one barrier/tile; Ps-LDS-free softmax (T12 cvt_pk + permlane32_swap);
// 32-key half-pipelines with p[16] softmax; DEN on the MFMA pipe via
// ones-B fragment (dacc in AGPRs).
// R12 delta (single change): NUM stored as f16 instead of f32.
//   - error math: NUM_z ~ sigma 18; f16 err 18*2^-11 ~ 0.009/part, RSS over
//     4 parts / DEN(~2048) -> ~1e-5 on out.  Negligible vs 2.44e-4 current.
//   - attn WRITE 34.3 -> 17.3 MB; reduce reads -16.8 MB; ws shrinks
//     49.5 -> 32.8 MB (tests the "ws memset in timed path" hypothesis
//     from the R0->R1 bucket delta).
// block 256 (4 waves x 32 q), grid (32, 8, ZS=4) = 1024 = 4/CU.
// ---------------------------------------------------------------------------
template<int ZS>
__global__ __launch_bounds__(256, 4) void attn_kernel(
    const ushort_t* __restrict__ Qb, const ushort_t* __restrict__ Kb,
    const ushort_t* __restrict__ Vt,
    f16_t* __restrict__ NUM, float* __restrict__ DEN)
{
    constexpr int KEYS = N_TOK / ZS;      // keys per block
    constexpr int TILES = KEYS / 64;      // 64-key tiles per block

    const int h = blockIdx.y;
    const int z = blockIdx.z;
    const int n0 = blockIdx.x * 128;
    const int tid = threadIdx.x;
    const int w = tid >> 6;               // 0..3, wave owns queries w*32..+31
    const int lane = tid & 63;
    const int l31 = lane & 31;
    const int hf = lane >> 5;             // half-wave: k-chunk select

    __shared__ ushort_t Ks[2 * 64 * 64];  // [buf][key][d], xor-swizzled chunks
    __shared__ ushort_t Vs[2 * 64 * 64];  // [buf][d][key], xor-swizzled chunks

    // Q B-fragments, register-resident (pre-scaled by -log2e).
    bf16x8 qb[4];
    {
        const ushort_t* base = Qb + (size_t)(n0 + w * 32 + l31) * PROJ + h * 64 + hf * 8;
        qb[0] = *(const bf16x8*)(base);
        qb[1] = *(const bf16x8*)(base + 16);
        qb[2] = *(const bf16x8*)(base + 32);
        qb[3] = *(const bf16x8*)(base + 48);
    }

    bf16x8 onesv;
#pragma unroll
    for (int j = 0; j < 8; ++j) onesv[j] = (__bf16)1.0f;

    f32x16 o0 = {};                       // O[q][d: 0..31]
    f32x16 o1 = {};                       // O[q][d: 32..63]
    f32x16 dacc = {};                     // DEN via MFMA-ones (R0-R2 proven)

    // DMA staging geometry: wave w covers rows w*16..w*16+15 in two issues
    // of 8 rows; lane -> (row = r0 + (lane>>3), physical chunk = lane&7).
    // Global source fetches logical chunk pc ^ (row&7) = pc ^ lrow.
    const int lrow = lane >> 3;
    const int pc = lane & 7;
    const int swz = (pc ^ lrow) * 8;      // shorts
    const int lb = w * 1024;              // wave's LDS base (shorts)
    const ushort_t* kg = Kb + (size_t)h * 64 +
                         ((size_t)z * KEYS + w * 16 + lrow) * PROJ + swz;
    const ushort_t* vg = Vt + ((size_t)h * 64 + w * 16 + lrow) * N_TOK +
                         (size_t)z * KEYS + swz;

    const int xm = l31 & 7;               // fragment-read swizzle mask

    // prologue: stage tile 0 -> buf 0 (drained by first loop barrier)
    gld_lds16(kg,             &Ks[lb]);
    gld_lds16(kg + 8 * PROJ,  &Ks[lb + 512]);
    gld_lds16(vg,             &Vs[lb]);
    gld_lds16(vg + 8 * N_TOK, &Vs[lb + 512]);
    kg += 64 * PROJ;
    vg += 64;

    for (int lt = 0; lt < TILES; ++lt) {
        const int bo = (lt & 1) << 12;    // read-buffer offset (shorts)
        __syncthreads();                  // vmcnt(0)+barrier: buf[lt&1] ready,
                                          // all waves done with buf[lt^1]
        if (lt + 1 < TILES) {             // DMA tile lt+1 into other buffer
            const int bw = ((lt + 1) & 1) << 12;
            gld_lds16(kg,             &Ks[bw + lb]);
            gld_lds16(kg + 8 * PROJ,  &Ks[bw + lb + 512]);
            gld_lds16(vg,             &Vs[bw + lb]);
            gld_lds16(vg + 8 * N_TOK, &Vs[bw + lb + 512]);
            kg += 64 * PROJ;
            vg += 64;
        }

        // ================= half A: keys 0-31 =================
        {
            f32x16 s0 = {};
            __builtin_amdgcn_s_setprio(1);
#pragma unroll
            for (int ks = 0; ks < 4; ++ks) {
                const int pos = ((ks * 2 + hf) ^ xm) * 8;
                bf16x8 ka = *(const bf16x8*)&Ks[bo + l31 * 64 + pos];
                s0 = __builtin_amdgcn_mfma_f32_32x32x16_bf16(ka, qb[ks], s0, 0, 0, 0);
            }
            __builtin_amdgcn_s_setprio(0);

            float p[16];
#pragma unroll
            for (int r = 0; r < 16; ++r) {
                p[r] = __builtin_amdgcn_rcpf(1.0f + __builtin_amdgcn_exp2f(s0[r]));
            }
            unsigned d00 = cvtpk_bf16(p[0],  p[1]);
            unsigned d01 = cvtpk_bf16(p[2],  p[3]);
            unsigned d10 = cvtpk_bf16(p[4],  p[5]);
            unsigned d11 = cvtpk_bf16(p[6],  p[7]);
            unsigned d20 = cvtpk_bf16(p[8],  p[9]);
            unsigned d21 = cvtpk_bf16(p[10], p[11]);
            unsigned d30 = cvtpk_bf16(p[12], p[13]);
            unsigned d31 = cvtpk_bf16(p[14], p[15]);
            PLSWAP(d00, d10);
            PLSWAP(d01, d11);
            PLSWAP(d20, d30);
            PLSWAP(d21, d31);
            union { unsigned u[4]; bf16x8 v; } A0, A1;
            A0.u[0] = d00; A0.u[1] = d01; A0.u[2] = d10; A0.u[3] = d11;
            A1.u[0] = d20; A1.u[1] = d21; A1.u[2] = d30; A1.u[3] = d31;

            __builtin_amdgcn_s_setprio(1);
            {
                const int pos = ((0 + hf) ^ xm) * 8;          // ks=0
                bf16x8 vb0 = *(const bf16x8*)&Vs[bo + l31 * 64 + pos];
                o0 = __builtin_amdgcn_mfma_f32_32x32x16_bf16(A0.v, vb0, o0, 0, 0, 0);
                bf16x8 vb1 = *(const bf16x8*)&Vs[bo + (32 + l31) * 64 + pos];
                o1 = __builtin_amdgcn_mfma_f32_32x32x16_bf16(A0.v, vb1, o1, 0, 0, 0);
            }
            dacc = __builtin_amdgcn_mfma_f32_32x32x16_bf16(A0.v, onesv, dacc, 0, 0, 0);
            {
                const int pos = ((2 + hf) ^ xm) * 8;          // ks=1
                bf16x8 vb0 = *(const bf16x8*)&Vs[bo + l31 * 64 + pos];
                o0 = __builtin_amdgcn_mfma_f32_32x32x16_bf16(A1.v, vb0, o0, 0, 0, 0);
                bf16x8 vb1 = *(const bf16x8*)&Vs[bo + (32 + l31) * 64 + pos];
                o1 = __builtin_amdgcn_mfma_f32_32x32x16_bf16(A1.v, vb1, o1, 0, 0, 0);
            }
            dacc = __builtin_amdgcn_mfma_f32_32x32x16_bf16(A1.v, onesv, dacc, 0, 0, 0);
            __builtin_amdgcn_s_setprio(0);
        }

        // ================= half B: keys 32-63 =================
        {
            f32x16 s1 = {};
            __builtin_amdgcn_s_setprio(1);
#pragma unroll
            for (int ks = 0; ks < 4; ++ks) {
                const int pos = ((ks * 2 + hf) ^ xm) * 8;
                bf16x8 ka = *(const bf16x8*)&Ks[bo + (32 + l31) * 64 + pos];
                s1 = __builtin_amdgcn_mfma_f32_32x32x16_bf16(ka, qb[ks], s1, 0, 0, 0);
            }
            __builtin_amdgcn_s_setprio(0);

            float p[16];
#pragma unroll
            for (int r = 0; r < 16; ++r) {
                p[r] = __builtin_amdgcn_rcpf(1.0f + __builtin_amdgcn_exp2f(s1[r]));
            }
            unsigned e00 = cvtpk_bf16(p[0],  p[1]);
            unsigned e01 = cvtpk_bf16(p[2],  p[3]);
            unsigned e10 = cvtpk_bf16(p[4],  p[5]);
            unsigned e11 = cvtpk_bf16(p[6],  p[7]);
            unsigned e20 = cvtpk_bf16(p[8],  p[9]);
            unsigned e21 = cvtpk_bf16(p[10], p[11]);
            unsigned e30 = cvtpk_bf16(p[12], p[13]);
            unsigned e31 = cvtpk_bf16(p[14], p[15]);
            PLSWAP(e00, e10);
            PLSWAP(e01, e11);
            PLSWAP(e20, e30);
            PLSWAP(e21, e31);
            union { unsigned u[4]; bf16x8 v; } A2, A3;
            A2.u[0] = e00; A2.u[1] = e01; A2.u[2] = e10; A2.u[3] = e11;
            A3.u[0] = e20; A3.u[1] = e21; A3.u[2] = e30; A3.u[3] = e31;

            __builtin_amdgcn_s_setprio(1);
            {
                const int pos = ((4 + hf) ^ xm) * 8;          // ks=2
                bf16x8 vb0 = *(const bf16x8*)&Vs[bo + l31 * 64 + pos];
                o0 = __builtin_amdgcn_mfma_f32_32x32x16_bf16(A2.v, vb0, o0, 0, 0, 0);
                bf16x8 vb1 = *(const bf16x8*)&Vs[bo + (32 + l31) * 64 + pos];
                o1 = __builtin_amdgcn_mfma_f32_32x32x16_bf16(A2.v, vb1, o1, 0, 0, 0);
            }
            dacc = __builtin_amdgcn_mfma_f32_32x32x16_bf16(A2.v, onesv, dacc, 0, 0, 0);
            {
                const int pos = ((6 + hf) ^ xm) * 8;          // ks=3
                bf16x8 vb0 = *(const bf16x8*)&Vs[bo + l31 * 64 + pos];
                o0 = __builtin_amdgcn_mfma_f32_32x32x16_bf16(A3.v, vb0, o0, 0, 0, 0);
                bf16x8 vb1 = *(const bf16x8*)&Vs[bo + (32 + l31) * 64 + pos];
                o1 = __builtin_amdgcn_mfma_f32_32x32x16_bf16(A3.v, vb1, o1, 0, 0, 0);
            }
            dacc = __builtin_amdgcn_mfma_f32_32x32x16_bf16(A3.v, onesv, dacc, 0, 0, 0);
            __builtin_amdgcn_s_setprio(0);
        }
    }

    // epilogue: unnormalized numerator (f16).  q-row = (r&3)+8*(r>>2)+4*hf
#pragma unroll
    for (int rq = 0; rq < 4; ++rq) {
#pragma unroll
        for (int j = 0; j < 4; ++j) {
            const int q = n0 + w * 32 + rq * 8 + hf * 4 + j;
            f16_t* np_ = &NUM[((size_t)z * N_TOK + q) * PROJ + h * 64 + l31];
            np_[0]  = (f16_t)o0[rq * 4 + j];
            np_[32] = (f16_t)o1[rq * 4 + j];
        }
    }
    // DEN from dacc: D[q][c] = sum_k P[q][k]*1, identical across cols c.
    // Lane col l31==0 of each half writes its 16 q-rows.
    if (l31 == 0) {
#pragma unroll
        for (int r = 0; r < 16; ++r) {
            const int q = n0 + w * 32 + (r & 3) + 8 * (r >> 2) + 4 * hf;
            DEN[((size_t)z * N_TOK + q) * HEADS + h] = dacc[r];
        }
    }
}

// ---------------------------------------------------------------------------
// Kernel 3: out[n][d] = (1/8) * sum_h (sum_z NUM_z)/(sum_z DEN_z)
// NUM is f16 (R12); DEN stays f32.
// ---------------------------------------------------------------------------
template<int ZS>
__global__ __launch_bounds__(256) void reduce_kernel(
    const f16_t* __restrict__ NUM, const float* __restrict__ DEN,
    float* __restrict__ out)
{
    const int g = blockIdx.x * 256 + threadIdx.x;
    const int n = g >> 6;
    const int d = g & 63;
    float acc = 0.0f;
#pragma unroll
    for (int hh = 0; hh < HEADS; ++hh) {
        float num = 0.0f, dd = 0.0f;
#pragma unroll
        for (int zz = 0; zz < ZS; ++zz) {
            num += (float)NUM[((size_t)zz * N_TOK + n) * PROJ + hh * 64 + d];
            dd  += DEN[((size_t)zz * N_TOK + n) * HEADS + hh];
        }
        acc += num / dd;
    }
    out[g] = acc * 0.125f;
}

extern "C" void kernel_launch(void* const* d_in, const int* in_sizes, int n_in,
                              void* d_out, int out_size, void* d_ws, size_t ws_size,
                              hipStream_t stream) {
    (void)in_sizes; (void)n_in; (void)out_size;
    const float* X  = (const float*)d_in[0];
    const float* Wq = (const float*)d_in[1];
    const float* bq = (const float*)d_in[2];
    const float* Wk = (const float*)d_in[3];
    const float* bk = (const float*)d_in[4];
    const float* Wv = (const float*)d_in[5];
    const float* bv = (const float*)d_in[6];
    float* out = (float*)d_out;

    // ws need at ZS=4: 16.78M (NUM f16) + 0.52M (DEN) + 12.58M (Qb/Kb/Vt)
    //                + 2.10M (Xa) + 0.79M (Wp) = 32.8 MB.  Fallback ZS=2.
    const size_t NEED4 =
        (size_t)4 * N_TOK * PROJ * 2 + (size_t)4 * N_TOK * HEADS * 4 +
        (size_t)3 * N_TOK * PROJ * 2 + (size_t)N_TOK * IN_CH * 2 +
        (size_t)3 * PROJ * IN_CH * 2;
    const int ZS = (ws_size >= NEED4) ? 4 : 2;

    f16_t* NUM = (f16_t*)d_ws;                              // [ZS][N][PROJ] f16
    float* DEN = (float*)(NUM + (size_t)ZS * N_TOK * PROJ); // [ZS][N][HEADS] f32
    ushort_t* Qb = (ushort_t*)(DEN + (size_t)ZS * N_TOK * HEADS);
    ushort_t* Kb = Qb + (size_t)N_TOK * PROJ;
    ushort_t* Vt = Kb + (size_t)N_TOK * PROJ;               // [H][64][N]
    ushort_t* Xa = Vt + (size_t)N_TOK * PROJ;               // frag-packed X
    ushort_t* Wp = Xa + (size_t)N_TOK * IN_CH;              // frag-packed W x3

    cast_pack_kernel<<<dim3(704), 256, 0, stream>>>(X, Wq, Wk, Wv, Xa, Wp);
    proj_mfma_kernel<<<dim3(PROJ / 64, N_TOK / 64, 3), 256, 0, stream>>>(
        Xa, Wp, bq, bk, bv, Qb, Kb, Vt);
    if (ZS == 4) {
        attn_kernel<4><<<dim3(N_TOK / 128, HEADS, 4), 256, 0, stream>>>(
            Qb, Kb, Vt, NUM, DEN);
        reduce_kernel<4><<<dim3(N_TOK * OUT_CH / 256), 256, 0, stream>>>(
            NUM, DEN, out);
    } else {
        attn_kernel<2><<<dim3(N_TOK / 128, HEADS, 2), 256, 0, stream>>>(
            Qb, Kb, Vt, NUM, DEN);
        reduce_kernel<2><<<dim3(N_TOK * OUT_CH / 256), 256, 0, stream>>>(
            NUM, DEN, out);
    }
}